// Round 4
// baseline (533.998 us; speedup 1.0000x reference)
//
#include <hip/hip_runtime.h>
#include <math.h>

#define SA 8      /* segments for kA */
#define SM 64     /* segments for mode-1 race kI */
#define NB 4096
#define TA 256    /* kA / kI threads */
#define TBB 1024  /* kB / kH threads */
#define SCT 256   /* scan threads (matches R3 chunk structure exactly) */
#define CH (NB / SCT) /* 16 */
#define CAPSEG 512
#define GTOT (SA * CAPSEG) /* 4096 */
#define EQC 64
#define FXS 1099511627776.0f /* 2^40 */
#define FXI (1.0f / 1099511627776.0f)

typedef unsigned u32;
typedef unsigned long long u64;

struct State {
  float m, Z2;
  int mode, k, r, eqn;
  u32 vstar;
  int eq[EQC];
};

struct ScanSh {
  u32 axc[SCT]; float axe[SCT];
  u32 sufc[SCT]; float sufe[SCT];
  int cbin[SCT]; u32 cca[SCT]; float cea[SCT];
  int fbin[SCT]; u32 fca[SCT]; float fea[SCT];
};

__device__ __forceinline__ u32 f2key(float f) {
  u32 u = __float_as_uint(f);
  return u ^ ((u >> 31) ? 0xFFFFFFFFu : 0x80000000u);
}
__device__ __forceinline__ float key2f(u32 k) {
  u32 u = (k & 0x80000000u) ? (k ^ 0x80000000u) : ~k;
  return __uint_as_float(u);
}
__device__ __forceinline__ int is_mode0(int k, int V) {
  return (k >= 1 && k <= 256 && k < V);
}

// R3-exact hierarchical crossing scan (mode-1 only), block-local version.
// esum[b] == (float)e0[b]*FXI, consumed exactly as R3's kC2/kD2 did.
__device__ void scan_level(const u32* cnt, const u64* e0, ScanSh* ax,
                           u32* sprefix, int* scnt_above, float* sexp_above,
                           float target, int level, int tid) {
  const u32 ca0 = (level == 0) ? 0u : (u32)*scnt_above;
  const float ea0 = (level == 0) ? 0.f : *sexp_above;
  if (tid < SCT) {
    u32 cc = 0; float ce = 0.f; const int base = tid * CH;
    for (int j = 0; j < CH; ++j) { cc += cnt[base + j]; ce += (float)e0[base + j] * FXI; }
    ax->axc[tid] = cc; ax->axe[tid] = ce;
  }
  __syncthreads();
  if (tid == 0) {
    u32 rc = 0; float re = 0.f;
    for (int c = SCT - 1; c >= 0; --c) {
      ax->sufc[c] = rc; ax->sufe[c] = re;
      rc += ax->axc[c]; re += ax->axe[c];
    }
  }
  __syncthreads();
  if (tid < SCT) {
    const int base = tid * CH;
    u32 rc = ax->sufc[tid]; float re = ax->sufe[tid];
    int best = -1; u32 bca = 0; float bea = 0.f;
    int fb = -1; u32 ffca = 0; float ffea = 0.f;
    for (int b = base + CH - 1; b >= base; --b) {
      u32 c = cnt[b]; float ebv = (float)e0[b] * FXI;
      bool cross = (c > 0) && (ea0 + (re + ebv) >= target);
      if (cross && best < 0) { best = b; bca = rc; bea = re; }
      if (c > 0) { fb = b; ffca = rc; ffea = re; }
      rc += c; re += ebv;
    }
    ax->cbin[tid] = best; ax->cca[tid] = bca; ax->cea[tid] = bea;
    ax->fbin[tid] = fb; ax->fca[tid] = ffca; ax->fea[tid] = ffea;
  }
  __syncthreads();
  if (tid == 0) {
    int bsel = -1; u32 ca = 0; float ea = 0.f;
    for (int c = 0; c < SCT; ++c) {
      int b = ax->cbin[c];
      if (b > bsel) { bsel = b; ca = ax->cca[c]; ea = ax->cea[c]; }
    }
    if (bsel < 0) {
      for (int c = 0; c < SCT; ++c) {
        int b = ax->fbin[c];
        if (b >= 0 && (bsel < 0 || b < bsel)) { bsel = b; ca = ax->fca[c]; ea = ax->fea[c]; }
      }
    }
    if (bsel < 0) bsel = 0;
    *sprefix = (level == 0) ? (u32)bsel : ((*sprefix << 12) | (u32)bsel);
    *scnt_above = (int)(ca0 + ca);
    *sexp_above = ea0 + ea;
  }
  __syncthreads();
}

// kA: per-(row,seg): seg max (plain store). Mode-0 rows additionally build a
// seg-local 4096-bin hist, pick the seg-local top-k threshold bin, and gather
// candidates with key >= bin start into fixed per-seg slots (plain stores).
__global__ __launch_bounds__(TA) void kA(const float* __restrict__ logits,
                                         const float* __restrict__ temps,
                                         const int* __restrict__ topks,
                                         float* __restrict__ maxpart,
                                         u32* __restrict__ scnt,
                                         float* __restrict__ candv,
                                         int* __restrict__ candi, int V) {
  const int row = blockIdx.x, seg = blockIdx.y, tid = threadIdx.x;
  __shared__ u32 cnt[NB];
  __shared__ float sm[TA];
  __shared__ u32 cs[TA];
  __shared__ int bb[TA];
  __shared__ int lcnt;
  __shared__ u32 sT;
  const int k = topks[row];
  const int m0 = is_mode0(k, V);
  const float t = temps[row];
  const float* lr = logits + (size_t)row * V;
  const float4* l4 = (const float4*)lr;
  const int n4 = V >> 2;
  const int q0 = (int)((long long)seg * n4 / SA);
  const int q1 = (int)((long long)(seg + 1) * n4 / SA);
  float mx = -INFINITY;
  if (m0) {
    for (int i = tid; i < NB; i += TA) cnt[i] = 0;
    if (tid == 0) lcnt = 0;
    __syncthreads();
    for (int i = q0 + tid; i < q1; i += TA) {
      float4 v = l4[i];
      float xs[4] = {v.x / t, v.y / t, v.z / t, v.w / t};
#pragma unroll
      for (int j = 0; j < 4; ++j) {
        mx = fmaxf(mx, xs[j]);
        atomicAdd(&cnt[f2key(xs[j]) >> 20], 1u);
      }
    }
    if (seg == SA - 1)
      for (int i = (n4 << 2) + tid; i < V; i += TA) {
        float x = lr[i] / t;
        mx = fmaxf(mx, x);
        atomicAdd(&cnt[f2key(x) >> 20], 1u);
      }
  } else {
    for (int i = q0 + tid; i < q1; i += TA) {
      float4 v = l4[i];
      mx = fmaxf(mx, fmaxf(fmaxf(v.x, v.y), fmaxf(v.z, v.w)) / t);
    }
    if (seg == SA - 1)
      for (int i = (n4 << 2) + tid; i < V; i += TA) mx = fmaxf(mx, lr[i] / t);
  }
  sm[tid] = mx;
  __syncthreads();
  for (int s = TA >> 1; s > 0; s >>= 1) {
    if (tid < s) sm[tid] = fmaxf(sm[tid], sm[tid + s]);
    __syncthreads();
  }
  if (tid == 0) maxpart[row * SA + seg] = sm[0];
  if (!m0) return;
  // seg-local threshold bin (same structure as R3 kB's proven crossing scan)
  {
    u32 cc = 0; const int base = tid * (NB / TA);
    for (int j = 0; j < NB / TA; ++j) cc += cnt[base + j];
    cs[tid] = cc;
  }
  __syncthreads();
  if (tid == 0) {
    u32 rc = 0;
    for (int c = TA - 1; c >= 0; --c) { u32 tmp = cs[c]; cs[c] = rc; rc += tmp; }
  }
  __syncthreads();
  const int kk = (k > 256) ? 256 : k;
  {
    const int base = tid * (NB / TA);
    u32 rc = cs[tid]; int best = -1;
    for (int b = base + NB / TA - 1; b >= base; --b) {
      u32 c = cnt[b];
      if (c && best < 0 && (int)(rc + c) >= kk) best = b;
      rc += c;
    }
    bb[tid] = best;
  }
  __syncthreads();
  if (tid == 0) {
    int bsel = -1;
    for (int c = 0; c < TA; ++c) if (bb[c] > bsel) bsel = bb[c];
    if (bsel < 0) { for (int b = 0; b < NB; ++b) if (cnt[b]) { bsel = b; break; } }
    if (bsel < 0) bsel = 0;
    sT = ((u32)bsel) << 20;
  }
  __syncthreads();
  const u32 T = sT;
  const size_t cbase = ((size_t)row * SA + seg) * CAPSEG;
  for (int i = q0 + tid; i < q1; i += TA) {
    float4 v = l4[i];
    float xs[4] = {v.x / t, v.y / t, v.z / t, v.w / t};
#pragma unroll
    for (int j = 0; j < 4; ++j) {
      if (f2key(xs[j]) >= T) {
        int s = atomicAdd(&lcnt, 1);
        if (s < CAPSEG) { candv[cbase + s] = xs[j]; candi[cbase + s] = i * 4 + j; }
      }
    }
  }
  if (seg == SA - 1)
    for (int i = (n4 << 2) + tid; i < V; i += TA) {
      float x = lr[i] / t;
      if (f2key(x) >= T) {
        int s = atomicAdd(&lcnt, 1);
        if (s < CAPSEG) { candv[cbase + s] = x; candi[cbase + s] = i; }
      }
    }
  __syncthreads();
  if (tid == 0) { int n = lcnt; if (n > CAPSEG) n = CAPSEG; scnt[row * SA + seg] = (u32)n; }
}

// kB: per-row. Mode decision + m. Mode-1 rows run the full 3-level scan +
// exact replay + boundary-tie collection in this single block.
__global__ __launch_bounds__(TBB) void kB(const float* __restrict__ logits,
                                          const float* __restrict__ temps,
                                          const int* __restrict__ topks,
                                          const float* __restrict__ topps,
                                          const float* __restrict__ maxpart,
                                          State* __restrict__ st,
                                          u64* __restrict__ rpack, int V) {
  const int row = blockIdx.x, tid = threadIdx.x;
  State* rs = &st[row];
  __shared__ u32 cnt[NB];
  __shared__ u64 e0[NB];
  __shared__ ScanSh ax;
  __shared__ u32 cnt2[256];
  __shared__ float eb[256], enb[256];
  __shared__ int eqi[EQC];
  __shared__ float wsum[TBB / 64];
  __shared__ float smax_, sS, sexp_above, starget;
  __shared__ u32 sprefix, svstar;
  __shared__ int scnt_above, sr, ecnt;
  const int k = topks[row];
  const int m0 = is_mode0(k, V);
  if (tid == 0) {
    float m = maxpart[row * SA];
    for (int j = 1; j < SA; ++j) m = fmaxf(m, maxpart[row * SA + j]);
    smax_ = m;
    rs->m = m; rs->mode = m0 ? 0 : 1; rs->k = k; rs->eqn = 0; rs->r = 0;
    if (!m0) rpack[row] = 0ull;
  }
  __syncthreads();
  if (m0) return;
  const float m = smax_;
  const float t = temps[row];
  const float p = topps[row];
  const float* lr = logits + (size_t)row * V;
  const float4* l4 = (const float4*)lr;
  const int n4 = V >> 2;
  // ---- scan 1: level-0 count + fixed-point esum + S
  for (int i = tid; i < NB; i += TBB) { cnt[i] = 0; e0[i] = 0ull; }
  __syncthreads();
  float ls = 0.f;
  for (int i = tid; i < n4; i += TBB) {
    float4 v = l4[i];
    float xs[4] = {v.x / t, v.y / t, v.z / t, v.w / t};
#pragma unroll
    for (int j = 0; j < 4; ++j) {
      float e = expf(xs[j] - m);
      ls += e;
      u32 b = f2key(xs[j]) >> 20;
      atomicAdd(&cnt[b], 1u);
      u64 fx = (u64)(e * FXS);
      if (fx) atomicAdd(&e0[b], fx);
    }
  }
  for (int i = (n4 << 2) + tid; i < V; i += TBB) {
    float x = lr[i] / t;
    float e = expf(x - m);
    ls += e;
    u32 b = f2key(x) >> 20;
    atomicAdd(&cnt[b], 1u);
    u64 fx = (u64)(e * FXS);
    if (fx) atomicAdd(&e0[b], fx);
  }
  for (int off = 32; off > 0; off >>= 1) ls += __shfl_down(ls, off, 64);
  if ((tid & 63) == 0) wsum[tid >> 6] = ls;
  __syncthreads();
  if (tid == 0) {
    float S = 0.f;
    for (int j = 0; j < TBB / 64; ++j) S += wsum[j];
    sS = S; starget = p * S;
  }
  __syncthreads();
  scan_level(cnt, e0, &ax, &sprefix, &scnt_above, &sexp_above, starget, 0, tid);
  // ---- scan 2: level-1 (middle 12 bits)
  const u32 pfx12 = sprefix;
  for (int i = tid; i < NB; i += TBB) { cnt[i] = 0; e0[i] = 0ull; }
  __syncthreads();
  for (int i = tid; i < n4; i += TBB) {
    float4 v = l4[i];
    float xs[4] = {v.x / t, v.y / t, v.z / t, v.w / t};
#pragma unroll
    for (int j = 0; j < 4; ++j) {
      u32 key = f2key(xs[j]);
      if ((key >> 20) == pfx12) {
        float e = expf(xs[j] - m);
        atomicAdd(&cnt[(key >> 8) & 0xFFFu], 1u);
        u64 fx = (u64)(e * FXS);
        if (fx) atomicAdd(&e0[(key >> 8) & 0xFFFu], fx);
      }
    }
  }
  for (int i = (n4 << 2) + tid; i < V; i += TBB) {
    float x = lr[i] / t;
    u32 key = f2key(x);
    if ((key >> 20) == pfx12) {
      float e = expf(x - m);
      atomicAdd(&cnt[(key >> 8) & 0xFFFu], 1u);
      u64 fx = (u64)(e * FXS);
      if (fx) atomicAdd(&e0[(key >> 8) & 0xFFFu], fx);
    }
  }
  __syncthreads();
  scan_level(cnt, e0, &ax, &sprefix, &scnt_above, &sexp_above, starget, 1, tid);
  // ---- scan 3: level-2 counts (last 8 bits)
  const u32 pfx24 = sprefix;
  if (tid < 256) cnt2[tid] = 0;
  __syncthreads();
  for (int i = tid; i < n4; i += TBB) {
    float4 v = l4[i];
    float xs[4] = {v.x / t, v.y / t, v.z / t, v.w / t};
#pragma unroll
    for (int j = 0; j < 4; ++j) {
      u32 key = f2key(xs[j]);
      if ((key >> 8) == pfx24) atomicAdd(&cnt2[key & 0xFFu], 1u);
    }
  }
  for (int i = (n4 << 2) + tid; i < V; i += TBB) {
    u32 key = f2key(lr[i] / t);
    if ((key >> 8) == pfx24) atomicAdd(&cnt2[key & 0xFFu], 1u);
  }
  __syncthreads();
  if (tid < 256) {
    u32 key = (pfx24 << 8) | (u32)tid;
    float v = key2f(key);
    float e = expf(v - m);
    eb[tid] = e; enb[tid] = e / sS;
  }
  __syncthreads();
  // ---- exact per-copy cumsum replay (R3 kE2 verbatim semantics)
  if (tid == 0) {
    float run_n = sexp_above / sS;
    float run_u = sexp_above;
    const int have_above = (scnt_above > 0);
    u32 lastkey = 0u; int lastr = 0; int anykept = 0;
    u32 vsel = 0u; int rsel = -1;
    for (int b = 255; b >= 0; --b) {
      int c = (int)cnt2[b];
      if (c == 0) continue;
      u32 key = (pfx24 << 8) | (u32)b;
      float e = eb[b]; float en = enb[b];
      int kept = 0;
      for (int q = 0; q < c; ++q) {
        float nn = run_n + en;
        if (nn < p) { run_n = nn; run_u += e; kept++; } else break;
      }
      if (kept == c) { lastkey = key; lastr = c; anykept = 1; continue; }
      if (kept > 0) { vsel = key; rsel = kept; }
      else if (anykept) { vsel = lastkey; rsel = lastr; }
      else if (have_above) { vsel = key; rsel = 0; }
      else { vsel = key; rsel = 1; run_u += e; }
      break;
    }
    if (rsel < 0) {
      if (anykept) { vsel = lastkey; rsel = lastr; }
      else { vsel = (pfx24 << 8); rsel = have_above ? 0 : 1; }
    }
    svstar = vsel; sr = rsel; ecnt = 0;
    rs->vstar = vsel; rs->r = rsel; rs->Z2 = run_u;
  }
  __syncthreads();
  // ---- scan 4: collect boundary ties (key == vstar), L2-hot
  const u32 vk = svstar;
  for (int i = tid; i < n4; i += TBB) {
    float4 v = l4[i];
    float xs[4] = {v.x / t, v.y / t, v.z / t, v.w / t};
#pragma unroll
    for (int j = 0; j < 4; ++j) {
      if (f2key(xs[j]) == vk) {
        int s = atomicAdd(&ecnt, 1);
        if (s < EQC) eqi[s] = i * 4 + j;
      }
    }
  }
  for (int i = (n4 << 2) + tid; i < V; i += TBB) {
    if (f2key(lr[i] / t) == vk) {
      int s = atomicAdd(&ecnt, 1);
      if (s < EQC) eqi[s] = i;
    }
  }
  __syncthreads();
  if (tid == 0) {
    int n = ecnt; if (n > EQC) n = EQC;
    for (int a = 1; a < n; ++a) {  // ascending index == stable-sort tie order
      int v = eqi[a]; int b2 = a - 1;
      while (b2 >= 0 && eqi[b2] > v) { eqi[b2 + 1] = eqi[b2]; --b2; }
      eqi[b2 + 1] = v;
    }
    int eqn = sr; if (eqn > n) eqn = n; if (eqn < 0) eqn = 0;
    for (int j = 0; j < eqn; ++j) rs->eq[j] = eqi[j];
    rs->eqn = eqn;
  }
}

// kH: mode-0 rows: merge per-seg candidate lists, rank-sort (value desc, index
// asc), exact reference replay (Zk -> cumsum -> J -> Z2), race over kept.
__global__ __launch_bounds__(TBB) void kH(const float* __restrict__ topps,
                                          const float* __restrict__ noise,
                                          const u32* __restrict__ scnt,
                                          const float* __restrict__ candv,
                                          const int* __restrict__ candi,
                                          const State* __restrict__ st,
                                          int* __restrict__ out, int V) {
  const int row = blockIdx.x, tid = threadIdx.x;
  const State* rs = &st[row];
  if (rs->mode != 0) return;
  __shared__ float gv[GTOT]; __shared__ int gi[GTOT];
  __shared__ float sv[CAPSEG]; __shared__ int si[CAPSEG];
  __shared__ float rr[TBB]; __shared__ int ri[TBB];
  __shared__ int offs[SA + 1];
  __shared__ int sJ; __shared__ float sZ2;
  if (tid == 0) {
    int o = 0;
    for (int s = 0; s < SA; ++s) {
      offs[s] = o;
      int c = (int)scnt[row * SA + s];
      if (c > CAPSEG) c = CAPSEG;
      if (c < 0) c = 0;
      o += c;
    }
    offs[SA] = o;
  }
  __syncthreads();
  const int g = offs[SA];
  for (int s = 0; s < SA; ++s) {
    const int o = offs[s], c = offs[s + 1] - o;
    const size_t cbase = ((size_t)row * SA + s) * CAPSEG;
    for (int i = tid; i < c; i += TBB) { gv[o + i] = candv[cbase + i]; gi[o + i] = candi[cbase + i]; }
  }
  __syncthreads();
  for (int i = tid; i < g; i += TBB) {
    float v = gv[i]; int ix = gi[i];
    int rank = 0;
    for (int j = 0; j < g; ++j) {
      float vj = gv[j]; int ij = gi[j];
      if (vj > v || (vj == v && ij < ix)) rank++;
    }
    if (rank < CAPSEG) { sv[rank] = v; si[rank] = ix; }
  }
  __syncthreads();
  const float m = rs->m;
  const float p = topps[row];
  if (tid == 0) {
    int keff = rs->k; if (keff > g) keff = g; if (keff > CAPSEG) keff = CAPSEG;
    int J = 1; float Z2 = 1.f;
    if (g > 0 && keff > 0) {
      float Zk = 0.f;
      for (int j = 0; j < keff; ++j) Zk += expf(sv[j] - m);
      float c = 0.f; J = 0;
      for (int j = 0; j < keff; ++j) {
        float pr = expf(sv[j] - m) / Zk;
        c += pr;
        if (c < p) J++; else break;
      }
      if (J < 1) J = 1;
      Z2 = 0.f;
      for (int j = 0; j < J; ++j) Z2 += expf(sv[j] - m);
    }
    sJ = J; sZ2 = Z2;
  }
  __syncthreads();
  const int J = sJ; const float Z2 = sZ2;
  float best = -1.f; int bidx = 0x7FFFFFFF;
  for (int j = tid; j < J && j < g; j += TBB) {
    int ix = si[j];
    float u = noise[(size_t)row * V + ix];
    float q = fmaxf(-logf(u), 1e-10f);
    float pr = expf(sv[j] - m) / Z2;
    float rt = pr / q;
    if (rt > best || (rt == best && ix < bidx)) { best = rt; bidx = ix; }
  }
  rr[tid] = best; ri[tid] = bidx;
  __syncthreads();
  for (int s = TBB >> 1; s > 0; s >>= 1) {
    if (tid < s) {
      float ov = rr[tid + s]; int oi = ri[tid + s];
      if (ov > rr[tid] || (ov == rr[tid] && oi < ri[tid])) { rr[tid] = ov; ri[tid] = oi; }
    }
    __syncthreads();
  }
  if (tid == 0) out[row] = (g > 0) ? ri[0] : 0;
}

// kI: mode-1 race over full row, packed (ratio_key, ~idx) atomicMax
__global__ __launch_bounds__(TA) void kI(const float* __restrict__ logits,
                                         const float* __restrict__ temps,
                                         const float* __restrict__ noise,
                                         const State* __restrict__ st,
                                         u64* __restrict__ rpack, int V) {
  const int row = blockIdx.x, seg = blockIdx.y, tid = threadIdx.x;
  const State* rs = &st[row];
  if (rs->mode != 1) return;
  __shared__ int eqs[EQC]; __shared__ int seqn;
  __shared__ float rr[TA]; __shared__ int ri[TA];
  if (tid == 0) {
    int nn = rs->eqn; if (nn > EQC) nn = EQC; if (nn < 0) nn = 0;
    seqn = nn;
    for (int i = 0; i < nn; ++i) eqs[i] = rs->eq[i];
  }
  __syncthreads();
  const float t = temps[row];
  const float m = rs->m;
  const float Z2 = rs->Z2;
  const u32 vk = rs->vstar;
  const int eqn = seqn;
  const float* lr = logits + (size_t)row * V;
  const float* ur = noise + (size_t)row * V;
  const float4* l4 = (const float4*)lr;
  const float4* u4 = (const float4*)ur;
  const int n4 = V >> 2;
  const int q0 = (int)((long long)seg * n4 / SM);
  const int q1 = (int)((long long)(seg + 1) * n4 / SM);
  float best = -1.f; int bidx = 0x7FFFFFFF;
  for (int i = q0 + tid; i < q1; i += TA) {
    float4 xv = l4[i];
    float4 uv = u4[i];
    float xs[4] = {xv.x / t, xv.y / t, xv.z / t, xv.w / t};
    float us[4] = {uv.x, uv.y, uv.z, uv.w};
#pragma unroll
    for (int j = 0; j < 4; ++j) {
      u32 key = f2key(xs[j]);
      bool kept = key > vk;
      if (!kept && key == vk) {
        int idx = i * 4 + j;
        for (int e = 0; e < eqn; ++e) if (eqs[e] == idx) { kept = true; break; }
      }
      if (kept) {
        float pr = expf(xs[j] - m) / Z2;
        float q = fmaxf(-logf(us[j]), 1e-10f);
        float rt = pr / q;
        int idx = i * 4 + j;
        if (rt > best || (rt == best && idx < bidx)) { best = rt; bidx = idx; }
      }
    }
  }
  if (seg == SM - 1)
    for (int i = (n4 << 2) + tid; i < V; i += TA) {
      float x = lr[i] / t;
      u32 key = f2key(x);
      bool kept = key > vk;
      if (!kept && key == vk) {
        for (int e = 0; e < eqn; ++e) if (eqs[e] == i) { kept = true; break; }
      }
      if (kept) {
        float pr = expf(x - m) / Z2;
        float q = fmaxf(-logf(ur[i]), 1e-10f);
        float rt = pr / q;
        if (rt > best || (rt == best && i < bidx)) { best = rt; bidx = i; }
      }
    }
  rr[tid] = best; ri[tid] = bidx;
  __syncthreads();
  for (int s = TA >> 1; s > 0; s >>= 1) {
    if (tid < s) {
      float ov = rr[tid + s]; int oi = ri[tid + s];
      if (ov > rr[tid] || (ov == rr[tid] && oi < ri[tid])) { rr[tid] = ov; ri[tid] = oi; }
    }
    __syncthreads();
  }
  if (tid == 0 && rr[0] >= 0.f) {
    u64 pk = ((u64)f2key(rr[0]) << 32) | (u64)(0xFFFFFFFFu - (u32)ri[0]);
    atomicMax(&rpack[row], pk);
  }
}

__global__ void kJ(const State* __restrict__ st, const u64* __restrict__ rpack,
                   int* __restrict__ out, int B) {
  int i = blockIdx.x * blockDim.x + threadIdx.x;
  if (i < B && st[i].mode == 1)
    out[i] = (int)(0xFFFFFFFFu - (u32)(rpack[i] & 0xFFFFFFFFull));
}

extern "C" void kernel_launch(void* const* d_in, const int* in_sizes, int n_in,
                              void* d_out, int out_size, void* d_ws, size_t ws_size,
                              hipStream_t stream) {
  const float* logits = (const float*)d_in[0];
  const float* temps = (const float*)d_in[1];
  const int* topks = (const int*)d_in[2];
  const float* topps = (const float*)d_in[3];
  const float* noise = (const float*)d_in[4];
  int* out = (int*)d_out;
  const int B = in_sizes[1];
  const int V = in_sizes[0] / B;
  (void)n_in; (void)out_size; (void)ws_size;

  u32* w = (u32*)d_ws;
  size_t o = 0;
  float* maxpart = (float*)(w + o); o += (size_t)B * SA;
  u32* scnt = w + o; o += (size_t)B * SA;
  float* candv = (float*)(w + o); o += (size_t)B * SA * CAPSEG;
  int* candi = (int*)(w + o); o += (size_t)B * SA * CAPSEG;
  if (o & 1) o += 1;
  u64* rpack = (u64*)(w + o); o += 2 * (size_t)B;
  State* st = (State*)(w + o);

  kA<<<dim3(B, SA), TA, 0, stream>>>(logits, temps, topks, maxpart, scnt, candv, candi, V);
  kB<<<B, TBB, 0, stream>>>(logits, temps, topks, topps, maxpart, st, rpack, V);
  kH<<<B, TBB, 0, stream>>>(topps, noise, scnt, candv, candi, st, out, V);
  kI<<<dim3(B, SM), TA, 0, stream>>>(logits, temps, noise, st, rpack, V);
  kJ<<<(B + 255) / 256, 256, 0, stream>>>(st, rpack, out, B);
}

// Round 5
// 365.460 us; speedup vs baseline: 1.4612x; 1.4612x over previous
//
#include <hip/hip_runtime.h>
#include <math.h>

#define SA 8      /* segments for kA */
#define SM 64     /* segments for mode-1 race kI */
#define NB 4096
#define TA 256    /* kA / kI threads */
#define TBB 1024  /* kB / kH threads */
#define SCT 256   /* scan threads (matches R3 chunk structure exactly) */
#define CH (NB / SCT) /* 16 */
#define CAPSEG 512
#define GTOT (SA * CAPSEG) /* 4096 */
#define EQC 64
#define FXS 1099511627776.0f /* 2^40 */
#define FXI (1.0f / 1099511627776.0f)

typedef unsigned u32;
typedef unsigned long long u64;

struct State {
  float m, Z2;
  int mode, k, r, eqn;
  u32 vstar;
  int eq[EQC];
};

struct ScanSh {
  u32 axc[SCT]; float axe[SCT];
  u32 sufc[SCT]; float sufe[SCT];
  int cbin[SCT]; u32 cca[SCT]; float cea[SCT];
  int fbin[SCT]; u32 fca[SCT]; float fea[SCT];
};

__device__ __forceinline__ u32 f2key(float f) {
  u32 u = __float_as_uint(f);
  return u ^ ((u >> 31) ? 0xFFFFFFFFu : 0x80000000u);
}
__device__ __forceinline__ float key2f(u32 k) {
  u32 u = (k & 0x80000000u) ? (k ^ 0x80000000u) : ~k;
  return __uint_as_float(u);
}
__device__ __forceinline__ int is_mode0(int k, int V) {
  return (k >= 1 && k <= 256 && k < V);
}

// R3-exact hierarchical crossing scan (mode-1 only), block-local version.
__device__ void scan_level(const u32* cnt, const u64* e0, ScanSh* ax,
                           u32* sprefix, int* scnt_above, float* sexp_above,
                           float target, int level, int tid) {
  const u32 ca0 = (level == 0) ? 0u : (u32)*scnt_above;
  const float ea0 = (level == 0) ? 0.f : *sexp_above;
  if (tid < SCT) {
    u32 cc = 0; float ce = 0.f; const int base = tid * CH;
    for (int j = 0; j < CH; ++j) { cc += cnt[base + j]; ce += (float)e0[base + j] * FXI; }
    ax->axc[tid] = cc; ax->axe[tid] = ce;
  }
  __syncthreads();
  if (tid == 0) {
    u32 rc = 0; float re = 0.f;
    for (int c = SCT - 1; c >= 0; --c) {
      ax->sufc[c] = rc; ax->sufe[c] = re;
      rc += ax->axc[c]; re += ax->axe[c];
    }
  }
  __syncthreads();
  if (tid < SCT) {
    const int base = tid * CH;
    u32 rc = ax->sufc[tid]; float re = ax->sufe[tid];
    int best = -1; u32 bca = 0; float bea = 0.f;
    int fb = -1; u32 ffca = 0; float ffea = 0.f;
    for (int b = base + CH - 1; b >= base; --b) {
      u32 c = cnt[b]; float ebv = (float)e0[b] * FXI;
      bool cross = (c > 0) && (ea0 + (re + ebv) >= target);
      if (cross && best < 0) { best = b; bca = rc; bea = re; }
      if (c > 0) { fb = b; ffca = rc; ffea = re; }
      rc += c; re += ebv;
    }
    ax->cbin[tid] = best; ax->cca[tid] = bca; ax->cea[tid] = bea;
    ax->fbin[tid] = fb; ax->fca[tid] = ffca; ax->fea[tid] = ffea;
  }
  __syncthreads();
  if (tid == 0) {
    int bsel = -1; u32 ca = 0; float ea = 0.f;
    for (int c = 0; c < SCT; ++c) {
      int b = ax->cbin[c];
      if (b > bsel) { bsel = b; ca = ax->cca[c]; ea = ax->cea[c]; }
    }
    if (bsel < 0) {
      for (int c = 0; c < SCT; ++c) {
        int b = ax->fbin[c];
        if (b >= 0 && (bsel < 0 || b < bsel)) { bsel = b; ca = ax->fca[c]; ea = ax->fea[c]; }
      }
    }
    if (bsel < 0) bsel = 0;
    *sprefix = (level == 0) ? (u32)bsel : ((*sprefix << 12) | (u32)bsel);
    *scnt_above = (int)(ca0 + ca);
    *sexp_above = ea0 + ea;
  }
  __syncthreads();
}

// kA: per-(row,seg): seg max; mode-0 rows also gather seg-local top-k superset
__global__ __launch_bounds__(TA) void kA(const float* __restrict__ logits,
                                         const float* __restrict__ temps,
                                         const int* __restrict__ topks,
                                         float* __restrict__ maxpart,
                                         u32* __restrict__ scnt,
                                         float* __restrict__ candv,
                                         int* __restrict__ candi, int V) {
  const int row = blockIdx.x, seg = blockIdx.y, tid = threadIdx.x;
  __shared__ u32 cnt[NB];
  __shared__ float sm[TA];
  __shared__ u32 cs[TA];
  __shared__ int bb[TA];
  __shared__ int lcnt;
  __shared__ u32 sT;
  const int k = topks[row];
  const int m0 = is_mode0(k, V);
  const float t = temps[row];
  const float* lr = logits + (size_t)row * V;
  const float4* l4 = (const float4*)lr;
  const int n4 = V >> 2;
  const int q0 = (int)((long long)seg * n4 / SA);
  const int q1 = (int)((long long)(seg + 1) * n4 / SA);
  float mx = -INFINITY;
  if (m0) {
    for (int i = tid; i < NB; i += TA) cnt[i] = 0;
    if (tid == 0) lcnt = 0;
    __syncthreads();
    for (int i = q0 + tid; i < q1; i += TA) {
      float4 v = l4[i];
      float xs[4] = {v.x / t, v.y / t, v.z / t, v.w / t};
#pragma unroll
      for (int j = 0; j < 4; ++j) {
        mx = fmaxf(mx, xs[j]);
        atomicAdd(&cnt[f2key(xs[j]) >> 20], 1u);
      }
    }
    if (seg == SA - 1)
      for (int i = (n4 << 2) + tid; i < V; i += TA) {
        float x = lr[i] / t;
        mx = fmaxf(mx, x);
        atomicAdd(&cnt[f2key(x) >> 20], 1u);
      }
  } else {
    for (int i = q0 + tid; i < q1; i += TA) {
      float4 v = l4[i];
      mx = fmaxf(mx, fmaxf(fmaxf(v.x, v.y), fmaxf(v.z, v.w)) / t);
    }
    if (seg == SA - 1)
      for (int i = (n4 << 2) + tid; i < V; i += TA) mx = fmaxf(mx, lr[i] / t);
  }
  sm[tid] = mx;
  __syncthreads();
  for (int s = TA >> 1; s > 0; s >>= 1) {
    if (tid < s) sm[tid] = fmaxf(sm[tid], sm[tid + s]);
    __syncthreads();
  }
  if (tid == 0) maxpart[row * SA + seg] = sm[0];
  if (!m0) return;
  {
    u32 cc = 0; const int base = tid * (NB / TA);
    for (int j = 0; j < NB / TA; ++j) cc += cnt[base + j];
    cs[tid] = cc;
  }
  __syncthreads();
  if (tid == 0) {
    u32 rc = 0;
    for (int c = TA - 1; c >= 0; --c) { u32 tmp = cs[c]; cs[c] = rc; rc += tmp; }
  }
  __syncthreads();
  const int kk = (k > 256) ? 256 : k;
  {
    const int base = tid * (NB / TA);
    u32 rc = cs[tid]; int best = -1;
    for (int b = base + NB / TA - 1; b >= base; --b) {
      u32 c = cnt[b];
      if (c && best < 0 && (int)(rc + c) >= kk) best = b;
      rc += c;
    }
    bb[tid] = best;
  }
  __syncthreads();
  if (tid == 0) {
    int bsel = -1;
    for (int c = 0; c < TA; ++c) if (bb[c] > bsel) bsel = bb[c];
    if (bsel < 0) { for (int b = 0; b < NB; ++b) if (cnt[b]) { bsel = b; break; } }
    if (bsel < 0) bsel = 0;
    sT = ((u32)bsel) << 20;
  }
  __syncthreads();
  const u32 T = sT;
  const size_t cbase = ((size_t)row * SA + seg) * CAPSEG;
  for (int i = q0 + tid; i < q1; i += TA) {
    float4 v = l4[i];
    float xs[4] = {v.x / t, v.y / t, v.z / t, v.w / t};
#pragma unroll
    for (int j = 0; j < 4; ++j) {
      if (f2key(xs[j]) >= T) {
        int s = atomicAdd(&lcnt, 1);
        if (s < CAPSEG) { candv[cbase + s] = xs[j]; candi[cbase + s] = i * 4 + j; }
      }
    }
  }
  if (seg == SA - 1)
    for (int i = (n4 << 2) + tid; i < V; i += TA) {
      float x = lr[i] / t;
      if (f2key(x) >= T) {
        int s = atomicAdd(&lcnt, 1);
        if (s < CAPSEG) { candv[cbase + s] = x; candi[cbase + s] = i; }
      }
    }
  __syncthreads();
  if (tid == 0) { int n = lcnt; if (n > CAPSEG) n = CAPSEG; scnt[row * SA + seg] = (u32)n; }
}

// kB: per-row: mode + m; mode-1 rows do full 3-level scan + replay + ties
__global__ __launch_bounds__(TBB) void kB(const float* __restrict__ logits,
                                          const float* __restrict__ temps,
                                          const int* __restrict__ topks,
                                          const float* __restrict__ topps,
                                          const float* __restrict__ maxpart,
                                          State* __restrict__ st,
                                          u64* __restrict__ rpack, int V) {
  const int row = blockIdx.x, tid = threadIdx.x;
  State* rs = &st[row];
  __shared__ u32 cnt[NB];
  __shared__ u64 e0[NB];
  __shared__ ScanSh ax;
  __shared__ u32 cnt2[256];
  __shared__ float eb[256], enb[256];
  __shared__ int eqi[EQC];
  __shared__ float wsum[TBB / 64];
  __shared__ float smax_, sS, sexp_above, starget;
  __shared__ u32 sprefix, svstar;
  __shared__ int scnt_above, sr, ecnt;
  const int k = topks[row];
  const int m0 = is_mode0(k, V);
  if (tid == 0) {
    float m = maxpart[row * SA];
    for (int j = 1; j < SA; ++j) m = fmaxf(m, maxpart[row * SA + j]);
    smax_ = m;
    rs->m = m; rs->mode = m0 ? 0 : 1; rs->k = k; rs->eqn = 0; rs->r = 0;
    if (!m0) rpack[row] = 0ull;
  }
  __syncthreads();
  if (m0) return;
  const float m = smax_;
  const float t = temps[row];
  const float p = topps[row];
  const float* lr = logits + (size_t)row * V;
  const float4* l4 = (const float4*)lr;
  const int n4 = V >> 2;
  for (int i = tid; i < NB; i += TBB) { cnt[i] = 0; e0[i] = 0ull; }
  __syncthreads();
  float ls = 0.f;
  for (int i = tid; i < n4; i += TBB) {
    float4 v = l4[i];
    float xs[4] = {v.x / t, v.y / t, v.z / t, v.w / t};
#pragma unroll
    for (int j = 0; j < 4; ++j) {
      float e = expf(xs[j] - m);
      ls += e;
      u32 b = f2key(xs[j]) >> 20;
      atomicAdd(&cnt[b], 1u);
      u64 fx = (u64)(e * FXS);
      if (fx) atomicAdd(&e0[b], fx);
    }
  }
  for (int i = (n4 << 2) + tid; i < V; i += TBB) {
    float x = lr[i] / t;
    float e = expf(x - m);
    ls += e;
    u32 b = f2key(x) >> 20;
    atomicAdd(&cnt[b], 1u);
    u64 fx = (u64)(e * FXS);
    if (fx) atomicAdd(&e0[b], fx);
  }
  for (int off = 32; off > 0; off >>= 1) ls += __shfl_down(ls, off, 64);
  if ((tid & 63) == 0) wsum[tid >> 6] = ls;
  __syncthreads();
  if (tid == 0) {
    float S = 0.f;
    for (int j = 0; j < TBB / 64; ++j) S += wsum[j];
    sS = S; starget = p * S;
  }
  __syncthreads();
  scan_level(cnt, e0, &ax, &sprefix, &scnt_above, &sexp_above, starget, 0, tid);
  const u32 pfx12 = sprefix;
  for (int i = tid; i < NB; i += TBB) { cnt[i] = 0; e0[i] = 0ull; }
  __syncthreads();
  for (int i = tid; i < n4; i += TBB) {
    float4 v = l4[i];
    float xs[4] = {v.x / t, v.y / t, v.z / t, v.w / t};
#pragma unroll
    for (int j = 0; j < 4; ++j) {
      u32 key = f2key(xs[j]);
      if ((key >> 20) == pfx12) {
        float e = expf(xs[j] - m);
        atomicAdd(&cnt[(key >> 8) & 0xFFFu], 1u);
        u64 fx = (u64)(e * FXS);
        if (fx) atomicAdd(&e0[(key >> 8) & 0xFFFu], fx);
      }
    }
  }
  for (int i = (n4 << 2) + tid; i < V; i += TBB) {
    float x = lr[i] / t;
    u32 key = f2key(x);
    if ((key >> 20) == pfx12) {
      float e = expf(x - m);
      atomicAdd(&cnt[(key >> 8) & 0xFFFu], 1u);
      u64 fx = (u64)(e * FXS);
      if (fx) atomicAdd(&e0[(key >> 8) & 0xFFFu], fx);
    }
  }
  __syncthreads();
  scan_level(cnt, e0, &ax, &sprefix, &scnt_above, &sexp_above, starget, 1, tid);
  const u32 pfx24 = sprefix;
  if (tid < 256) cnt2[tid] = 0;
  __syncthreads();
  for (int i = tid; i < n4; i += TBB) {
    float4 v = l4[i];
    float xs[4] = {v.x / t, v.y / t, v.z / t, v.w / t};
#pragma unroll
    for (int j = 0; j < 4; ++j) {
      u32 key = f2key(xs[j]);
      if ((key >> 8) == pfx24) atomicAdd(&cnt2[key & 0xFFu], 1u);
    }
  }
  for (int i = (n4 << 2) + tid; i < V; i += TBB) {
    u32 key = f2key(lr[i] / t);
    if ((key >> 8) == pfx24) atomicAdd(&cnt2[key & 0xFFu], 1u);
  }
  __syncthreads();
  if (tid < 256) {
    u32 key = (pfx24 << 8) | (u32)tid;
    float v = key2f(key);
    float e = expf(v - m);
    eb[tid] = e; enb[tid] = e / sS;
  }
  __syncthreads();
  if (tid == 0) {
    float run_n = sexp_above / sS;
    float run_u = sexp_above;
    const int have_above = (scnt_above > 0);
    u32 lastkey = 0u; int lastr = 0; int anykept = 0;
    u32 vsel = 0u; int rsel = -1;
    for (int b = 255; b >= 0; --b) {
      int c = (int)cnt2[b];
      if (c == 0) continue;
      u32 key = (pfx24 << 8) | (u32)b;
      float e = eb[b]; float en = enb[b];
      int kept = 0;
      for (int q = 0; q < c; ++q) {
        float nn = run_n + en;
        if (nn < p) { run_n = nn; run_u += e; kept++; } else break;
      }
      if (kept == c) { lastkey = key; lastr = c; anykept = 1; continue; }
      if (kept > 0) { vsel = key; rsel = kept; }
      else if (anykept) { vsel = lastkey; rsel = lastr; }
      else if (have_above) { vsel = key; rsel = 0; }
      else { vsel = key; rsel = 1; run_u += e; }
      break;
    }
    if (rsel < 0) {
      if (anykept) { vsel = lastkey; rsel = lastr; }
      else { vsel = (pfx24 << 8); rsel = have_above ? 0 : 1; }
    }
    svstar = vsel; sr = rsel; ecnt = 0;
    rs->vstar = vsel; rs->r = rsel; rs->Z2 = run_u;
  }
  __syncthreads();
  const u32 vk = svstar;
  for (int i = tid; i < n4; i += TBB) {
    float4 v = l4[i];
    float xs[4] = {v.x / t, v.y / t, v.z / t, v.w / t};
#pragma unroll
    for (int j = 0; j < 4; ++j) {
      if (f2key(xs[j]) == vk) {
        int s = atomicAdd(&ecnt, 1);
        if (s < EQC) eqi[s] = i * 4 + j;
      }
    }
  }
  for (int i = (n4 << 2) + tid; i < V; i += TBB) {
    if (f2key(lr[i] / t) == vk) {
      int s = atomicAdd(&ecnt, 1);
      if (s < EQC) eqi[s] = i;
    }
  }
  __syncthreads();
  if (tid == 0) {
    int n = ecnt; if (n > EQC) n = EQC;
    for (int a = 1; a < n; ++a) {
      int v = eqi[a]; int b2 = a - 1;
      while (b2 >= 0 && eqi[b2] > v) { eqi[b2 + 1] = eqi[b2]; --b2; }
      eqi[b2 + 1] = v;
    }
    int eqn = sr; if (eqn > n) eqn = n; if (eqn < 0) eqn = 0;
    for (int j = 0; j < eqn; ++j) rs->eq[j] = eqi[j];
    rs->eqn = eqn;
  }
}

// kH: mode-0: merge per-seg candidates, exact radix-select kk-th key,
// compact survivors (key >= key_kk), rank-sort, exact replay, race.
__global__ __launch_bounds__(TBB) void kH(const float* __restrict__ topps,
                                          const float* __restrict__ noise,
                                          const u32* __restrict__ scnt,
                                          const float* __restrict__ candv,
                                          const int* __restrict__ candi,
                                          const State* __restrict__ st,
                                          int* __restrict__ out, int V) {
  const int row = blockIdx.x, tid = threadIdx.x;
  const State* rs = &st[row];
  if (rs->mode != 0) return;
  __shared__ float gv[GTOT]; __shared__ int gi[GTOT];
  __shared__ float sv[CAPSEG]; __shared__ int si[CAPSEG];
  __shared__ float fv[CAPSEG]; __shared__ int fi[CAPSEG];
  __shared__ float rr[TBB]; __shared__ int ri[TBB];
  __shared__ int offs[SA + 1];
  __shared__ u32 dh[256];
  __shared__ u32 sPrefix; __shared__ int sRemain, sNf;
  __shared__ int sJ; __shared__ float sZ2;
  if (tid == 0) {
    int o = 0;
    for (int s = 0; s < SA; ++s) {
      offs[s] = o;
      int c = (int)scnt[row * SA + s];
      if (c > CAPSEG) c = CAPSEG;
      if (c < 0) c = 0;
      o += c;
    }
    offs[SA] = o;
  }
  __syncthreads();
  const int g = offs[SA];
  for (int s = 0; s < SA; ++s) {
    const int o = offs[s], c = offs[s + 1] - o;
    const size_t cbase = ((size_t)row * SA + s) * CAPSEG;
    for (int i = tid; i < c; i += TBB) { gv[o + i] = candv[cbase + i]; gi[o + i] = candi[cbase + i]; }
  }
  __syncthreads();
  int kk = rs->k; if (kk > 256) kk = 256; if (kk > g) kk = g;
  // ---- exact radix select: key of the kk-th largest candidate (dup-counting)
  if (tid == 0) { sPrefix = 0u; sRemain = (kk < 1) ? 1 : kk; }
  __syncthreads();
  for (int pass = 0; pass < 4; ++pass) {
    const int shift = 24 - 8 * pass;
    if (tid < 256) dh[tid] = 0;
    __syncthreads();
    const u32 pref = sPrefix;
    for (int i = tid; i < g; i += TBB) {
      u32 key = f2key(gv[i]);
      if (pass == 0 || (key >> (shift + 8)) == pref)
        atomicAdd(&dh[(key >> shift) & 0xFFu], 1u);
    }
    __syncthreads();
    if (tid == 0) {
      u32 rc = 0; int d = 255;
      for (; d >= 0; --d) {
        if (rc + dh[d] >= (u32)sRemain) break;
        rc += dh[d];
      }
      if (d < 0) d = 0;
      sRemain -= (int)rc;
      sPrefix = (sPrefix << 8) | (u32)d;
      if (pass == 3) sNf = 0;
    }
    __syncthreads();
  }
  const u32 Tk = sPrefix;
  // ---- compact survivors (all candidates >= kk-th largest, incl. all ties)
  for (int i = tid; i < g; i += TBB) {
    if (f2key(gv[i]) >= Tk) {
      int s = atomicAdd(&sNf, 1);
      if (s < CAPSEG) { fv[s] = gv[i]; fi[s] = gi[i]; }
    }
  }
  __syncthreads();
  int nf = sNf; if (nf > CAPSEG) nf = CAPSEG;
  // ---- rank sort by (value desc, index asc) == stable argsort(-x)
  for (int i = tid; i < nf; i += TBB) {
    float v = fv[i]; int ix = fi[i];
    int rank = 0;
    for (int j = 0; j < nf; ++j) {
      float vj = fv[j]; int ij = fi[j];
      if (vj > v || (vj == v && ij < ix)) rank++;
    }
    sv[rank] = v; si[rank] = ix;
  }
  __syncthreads();
  const float m = rs->m;
  const float p = topps[row];
  if (tid == 0) {
    int keff = rs->k; if (keff > nf) keff = nf;
    int J = 1; float Z2 = 1.f;
    if (nf > 0 && keff > 0) {
      float Zk = 0.f;
      for (int j = 0; j < keff; ++j) Zk += expf(sv[j] - m);
      float c = 0.f; J = 0;
      for (int j = 0; j < keff; ++j) {
        float pr = expf(sv[j] - m) / Zk;
        c += pr;
        if (c < p) J++; else break;
      }
      if (J < 1) J = 1;
      Z2 = 0.f;
      for (int j = 0; j < J; ++j) Z2 += expf(sv[j] - m);
    }
    sJ = J; sZ2 = Z2;
  }
  __syncthreads();
  const int J = sJ; const float Z2 = sZ2;
  float best = -1.f; int bidx = 0x7FFFFFFF;
  for (int j = tid; j < J && j < nf; j += TBB) {
    int ix = si[j];
    float u = noise[(size_t)row * V + ix];
    float q = fmaxf(-logf(u), 1e-10f);
    float pr = expf(sv[j] - m) / Z2;
    float rt = pr / q;
    if (rt > best || (rt == best && ix < bidx)) { best = rt; bidx = ix; }
  }
  rr[tid] = best; ri[tid] = bidx;
  __syncthreads();
  for (int s = TBB >> 1; s > 0; s >>= 1) {
    if (tid < s) {
      float ov = rr[tid + s]; int oi = ri[tid + s];
      if (ov > rr[tid] || (ov == rr[tid] && oi < ri[tid])) { rr[tid] = ov; ri[tid] = oi; }
    }
    __syncthreads();
  }
  if (tid == 0) out[row] = (nf > 0) ? ri[0] : 0;
}

// kI: mode-1 race over full row, packed (ratio_key, ~idx) atomicMax
__global__ __launch_bounds__(TA) void kI(const float* __restrict__ logits,
                                         const float* __restrict__ temps,
                                         const float* __restrict__ noise,
                                         const State* __restrict__ st,
                                         u64* __restrict__ rpack, int V) {
  const int row = blockIdx.x, seg = blockIdx.y, tid = threadIdx.x;
  const State* rs = &st[row];
  if (rs->mode != 1) return;
  __shared__ int eqs[EQC]; __shared__ int seqn;
  __shared__ float rr[TA]; __shared__ int ri[TA];
  if (tid == 0) {
    int nn = rs->eqn; if (nn > EQC) nn = EQC; if (nn < 0) nn = 0;
    seqn = nn;
    for (int i = 0; i < nn; ++i) eqs[i] = rs->eq[i];
  }
  __syncthreads();
  const float t = temps[row];
  const float m = rs->m;
  const float Z2 = rs->Z2;
  const u32 vk = rs->vstar;
  const int eqn = seqn;
  const float* lr = logits + (size_t)row * V;
  const float* ur = noise + (size_t)row * V;
  const float4* l4 = (const float4*)lr;
  const float4* u4 = (const float4*)ur;
  const int n4 = V >> 2;
  const int q0 = (int)((long long)seg * n4 / SM);
  const int q1 = (int)((long long)(seg + 1) * n4 / SM);
  float best = -1.f; int bidx = 0x7FFFFFFF;
  for (int i = q0 + tid; i < q1; i += TA) {
    float4 xv = l4[i];
    float4 uv = u4[i];
    float xs[4] = {xv.x / t, xv.y / t, xv.z / t, xv.w / t};
    float us[4] = {uv.x, uv.y, uv.z, uv.w};
#pragma unroll
    for (int j = 0; j < 4; ++j) {
      u32 key = f2key(xs[j]);
      bool kept = key > vk;
      if (!kept && key == vk) {
        int idx = i * 4 + j;
        for (int e = 0; e < eqn; ++e) if (eqs[e] == idx) { kept = true; break; }
      }
      if (kept) {
        float pr = expf(xs[j] - m) / Z2;
        float q = fmaxf(-logf(us[j]), 1e-10f);
        float rt = pr / q;
        int idx = i * 4 + j;
        if (rt > best || (rt == best && idx < bidx)) { best = rt; bidx = idx; }
      }
    }
  }
  if (seg == SM - 1)
    for (int i = (n4 << 2) + tid; i < V; i += TA) {
      float x = lr[i] / t;
      u32 key = f2key(x);
      bool kept = key > vk;
      if (!kept && key == vk) {
        for (int e = 0; e < eqn; ++e) if (eqs[e] == i) { kept = true; break; }
      }
      if (kept) {
        float pr = expf(x - m) / Z2;
        float q = fmaxf(-logf(ur[i]), 1e-10f);
        float rt = pr / q;
        if (rt > best || (rt == best && i < bidx)) { best = rt; bidx = i; }
      }
    }
  rr[tid] = best; ri[tid] = bidx;
  __syncthreads();
  for (int s = TA >> 1; s > 0; s >>= 1) {
    if (tid < s) {
      float ov = rr[tid + s]; int oi = ri[tid + s];
      if (ov > rr[tid] || (ov == rr[tid] && oi < ri[tid])) { rr[tid] = ov; ri[tid] = oi; }
    }
    __syncthreads();
  }
  if (tid == 0 && rr[0] >= 0.f) {
    u64 pk = ((u64)f2key(rr[0]) << 32) | (u64)(0xFFFFFFFFu - (u32)ri[0]);
    atomicMax(&rpack[row], pk);
  }
}

__global__ void kJ(const State* __restrict__ st, const u64* __restrict__ rpack,
                   int* __restrict__ out, int B) {
  int i = blockIdx.x * blockDim.x + threadIdx.x;
  if (i < B && st[i].mode == 1)
    out[i] = (int)(0xFFFFFFFFu - (u32)(rpack[i] & 0xFFFFFFFFull));
}

extern "C" void kernel_launch(void* const* d_in, const int* in_sizes, int n_in,
                              void* d_out, int out_size, void* d_ws, size_t ws_size,
                              hipStream_t stream) {
  const float* logits = (const float*)d_in[0];
  const float* temps = (const float*)d_in[1];
  const int* topks = (const int*)d_in[2];
  const float* topps = (const float*)d_in[3];
  const float* noise = (const float*)d_in[4];
  int* out = (int*)d_out;
  const int B = in_sizes[1];
  const int V = in_sizes[0] / B;
  (void)n_in; (void)out_size; (void)ws_size;

  u32* w = (u32*)d_ws;
  size_t o = 0;
  float* maxpart = (float*)(w + o); o += (size_t)B * SA;
  u32* scnt = w + o; o += (size_t)B * SA;
  float* candv = (float*)(w + o); o += (size_t)B * SA * CAPSEG;
  int* candi = (int*)(w + o); o += (size_t)B * SA * CAPSEG;
  if (o & 1) o += 1;
  u64* rpack = (u64*)(w + o); o += 2 * (size_t)B;
  State* st = (State*)(w + o);

  kA<<<dim3(B, SA), TA, 0, stream>>>(logits, temps, topks, maxpart, scnt, candv, candi, V);
  kB<<<B, TBB, 0, stream>>>(logits, temps, topks, topps, maxpart, st, rpack, V);
  kH<<<B, TBB, 0, stream>>>(topps, noise, scnt, candv, candi, st, out, V);
  kI<<<dim3(B, SM), TA, 0, stream>>>(logits, temps, noise, st, rpack, V);
  kJ<<<(B + 255) / 256, 256, 0, stream>>>(st, rpack, out, B);
}

// Round 6
// 323.925 us; speedup vs baseline: 1.6485x; 1.1282x over previous
//
#include <hip/hip_runtime.h>
#include <math.h>

#define SA 8      /* segments for kA */
#define SM 64     /* segments for mode-1 kernels kC/kD/kI */
#define NB 4096
#define TA 256    /* kA / kI / kC / kC2 / kD threads */
#define TBB 1024  /* kB / kH / kD2 threads */
#define SCT 256   /* scan threads (matches R3 chunk structure exactly) */
#define CH (NB / SCT) /* 16 */
#define CAPSEG 512
#define GTOT (SA * CAPSEG) /* 4096 */
#define MAXM1 16
#define GB1 16384 /* gathered crossing-bin cap per mode-1 row */
#define SUBC 512  /* sub-bin cap */
#define EQC 64
#define FXS 1099511627776.0f /* 2^40 */
#define FXI (1.0f / 1099511627776.0f)

typedef unsigned u32;
typedef unsigned long long u64;

struct State {
  float m, Z2;
  int mode, k, r, eqn;
  u32 vstar;
  int eq[EQC];
};

struct Aux1 {
  u32 pfx;      // 12-bit level-0 prefix
  int ca;       // cnt_above after level 0
  float ea;     // exp_above after level 0
  float S;
  float target; // p * S
};

struct ScanSh {
  u32 axc[SCT]; float axe[SCT];
  u32 sufc[SCT]; float sufe[SCT];
  int cbin[SCT]; u32 cca[SCT]; float cea[SCT];
  int fbin[SCT]; u32 fca[SCT]; float fea[SCT];
};

__device__ __forceinline__ u32 f2key(float f) {
  u32 u = __float_as_uint(f);
  return u ^ ((u >> 31) ? 0xFFFFFFFFu : 0x80000000u);
}
__device__ __forceinline__ float key2f(u32 k) {
  u32 u = (k & 0x80000000u) ? (k ^ 0x80000000u) : ~k;
  return __uint_as_float(u);
}
__device__ __forceinline__ int is_mode0(int k, int V) {
  return (k >= 1 && k <= 256 && k < V);
}

// R3-proven level-0 crossing scan (mode-1), 256-thread structure.
__device__ void scan_level(const u32* cnt, const u64* e0, ScanSh* ax,
                           u32* sprefix, int* scnt_above, float* sexp_above,
                           float target, int tid) {
  if (tid < SCT) {
    u32 cc = 0; float ce = 0.f; const int base = tid * CH;
    for (int j = 0; j < CH; ++j) { cc += cnt[base + j]; ce += (float)e0[base + j] * FXI; }
    ax->axc[tid] = cc; ax->axe[tid] = ce;
  }
  __syncthreads();
  if (tid == 0) {
    u32 rc = 0; float re = 0.f;
    for (int c = SCT - 1; c >= 0; --c) {
      ax->sufc[c] = rc; ax->sufe[c] = re;
      rc += ax->axc[c]; re += ax->axe[c];
    }
  }
  __syncthreads();
  if (tid < SCT) {
    const int base = tid * CH;
    u32 rc = ax->sufc[tid]; float re = ax->sufe[tid];
    int best = -1; u32 bca = 0; float bea = 0.f;
    int fb = -1; u32 ffca = 0; float ffea = 0.f;
    for (int b = base + CH - 1; b >= base; --b) {
      u32 c = cnt[b]; float ebv = (float)e0[b] * FXI;
      bool cross = (c > 0) && ((re + ebv) >= target);
      if (cross && best < 0) { best = b; bca = rc; bea = re; }
      if (c > 0) { fb = b; ffca = rc; ffea = re; }
      rc += c; re += ebv;
    }
    ax->cbin[tid] = best; ax->cca[tid] = bca; ax->cea[tid] = bea;
    ax->fbin[tid] = fb; ax->fca[tid] = ffca; ax->fea[tid] = ffea;
  }
  __syncthreads();
  if (tid == 0) {
    int bsel = -1; u32 ca = 0; float ea = 0.f;
    for (int c = 0; c < SCT; ++c) {
      int b = ax->cbin[c];
      if (b > bsel) { bsel = b; ca = ax->cca[c]; ea = ax->cea[c]; }
    }
    if (bsel < 0) {
      for (int c = 0; c < SCT; ++c) {
        int b = ax->fbin[c];
        if (b >= 0 && (bsel < 0 || b < bsel)) { bsel = b; ca = ax->fca[c]; ea = ax->fea[c]; }
      }
    }
    if (bsel < 0) bsel = 0;
    *sprefix = (u32)bsel;
    *scnt_above = (int)ca;
    *sexp_above = ea;
  }
  __syncthreads();
}

// kA: per-(row,seg): seg max; mode-0 rows also gather seg-local top-k superset
__global__ __launch_bounds__(TA) void kA(const float* __restrict__ logits,
                                         const float* __restrict__ temps,
                                         const int* __restrict__ topks,
                                         float* __restrict__ maxpart,
                                         u32* __restrict__ scnt,
                                         float* __restrict__ candv,
                                         int* __restrict__ candi,
                                         u32* __restrict__ nm1, int V) {
  const int row = blockIdx.x, seg = blockIdx.y, tid = threadIdx.x;
  __shared__ u32 cnt[NB];
  __shared__ float sm[TA];
  __shared__ u32 cs[TA];
  __shared__ int bb[TA];
  __shared__ int lcnt;
  __shared__ u32 sT;
  if (row == 0 && seg == 0 && tid == 0) nm1[0] = 0;
  const int k = topks[row];
  const int m0 = is_mode0(k, V);
  const float t = temps[row];
  const float* lr = logits + (size_t)row * V;
  const float4* l4 = (const float4*)lr;
  const int n4 = V >> 2;
  const int q0 = (int)((long long)seg * n4 / SA);
  const int q1 = (int)((long long)(seg + 1) * n4 / SA);
  float mx = -INFINITY;
  if (m0) {
    for (int i = tid; i < NB; i += TA) cnt[i] = 0;
    if (tid == 0) lcnt = 0;
    __syncthreads();
    for (int i = q0 + tid; i < q1; i += TA) {
      float4 v = l4[i];
      float xs[4] = {v.x / t, v.y / t, v.z / t, v.w / t};
#pragma unroll
      for (int j = 0; j < 4; ++j) {
        mx = fmaxf(mx, xs[j]);
        atomicAdd(&cnt[f2key(xs[j]) >> 20], 1u);
      }
    }
    if (seg == SA - 1)
      for (int i = (n4 << 2) + tid; i < V; i += TA) {
        float x = lr[i] / t;
        mx = fmaxf(mx, x);
        atomicAdd(&cnt[f2key(x) >> 20], 1u);
      }
  } else {
    for (int i = q0 + tid; i < q1; i += TA) {
      float4 v = l4[i];
      mx = fmaxf(mx, fmaxf(fmaxf(v.x, v.y), fmaxf(v.z, v.w)) / t);
    }
    if (seg == SA - 1)
      for (int i = (n4 << 2) + tid; i < V; i += TA) mx = fmaxf(mx, lr[i] / t);
  }
  sm[tid] = mx;
  __syncthreads();
  for (int s = TA >> 1; s > 0; s >>= 1) {
    if (tid < s) sm[tid] = fmaxf(sm[tid], sm[tid + s]);
    __syncthreads();
  }
  if (tid == 0) maxpart[row * SA + seg] = sm[0];
  if (!m0) return;
  {
    u32 cc = 0; const int base = tid * (NB / TA);
    for (int j = 0; j < NB / TA; ++j) cc += cnt[base + j];
    cs[tid] = cc;
  }
  __syncthreads();
  if (tid == 0) {
    u32 rc = 0;
    for (int c = TA - 1; c >= 0; --c) { u32 tmp = cs[c]; cs[c] = rc; rc += tmp; }
  }
  __syncthreads();
  const int kk = (k > 256) ? 256 : k;
  {
    const int base = tid * (NB / TA);
    u32 rc = cs[tid]; int best = -1;
    for (int b = base + NB / TA - 1; b >= base; --b) {
      u32 c = cnt[b];
      if (c && best < 0 && (int)(rc + c) >= kk) best = b;
      rc += c;
    }
    bb[tid] = best;
  }
  __syncthreads();
  if (tid == 0) {
    int bsel = -1;
    for (int c = 0; c < TA; ++c) if (bb[c] > bsel) bsel = bb[c];
    if (bsel < 0) { for (int b = 0; b < NB; ++b) if (cnt[b]) { bsel = b; break; } }
    if (bsel < 0) bsel = 0;
    sT = ((u32)bsel) << 20;
  }
  __syncthreads();
  const u32 T = sT;
  const size_t cbase = ((size_t)row * SA + seg) * CAPSEG;
  for (int i = q0 + tid; i < q1; i += TA) {
    float4 v = l4[i];
    float xs[4] = {v.x / t, v.y / t, v.z / t, v.w / t};
#pragma unroll
    for (int j = 0; j < 4; ++j) {
      if (f2key(xs[j]) >= T) {
        int s = atomicAdd(&lcnt, 1);
        if (s < CAPSEG) { candv[cbase + s] = xs[j]; candi[cbase + s] = i * 4 + j; }
      }
    }
  }
  if (seg == SA - 1)
    for (int i = (n4 << 2) + tid; i < V; i += TA) {
      float x = lr[i] / t;
      if (f2key(x) >= T) {
        int s = atomicAdd(&lcnt, 1);
        if (s < CAPSEG) { candv[cbase + s] = x; candi[cbase + s] = i; }
      }
    }
  __syncthreads();
  if (tid == 0) { int n = lcnt; if (n > CAPSEG) n = CAPSEG; scnt[row * SA + seg] = (u32)n; }
}

// kB: light per-row: mode + m + compact mode-1 rows + zero mode-1 accumulators
__global__ __launch_bounds__(TBB) void kB(const int* __restrict__ topks,
                                          const float* __restrict__ maxpart,
                                          State* __restrict__ st,
                                          u64* __restrict__ rpack,
                                          u32* __restrict__ nm1,
                                          u32* __restrict__ m1rows,
                                          u32* __restrict__ zp, size_t zwords, int V) {
  const int row = blockIdx.x, tid = threadIdx.x;
  State* rs = &st[row];
  const int k = topks[row];
  const int m0 = is_mode0(k, V);
  if (tid == 0) {
    float m = maxpart[row * SA];
    for (int j = 1; j < SA; ++j) m = fmaxf(m, maxpart[row * SA + j]);
    rs->m = m; rs->mode = m0 ? 0 : 1; rs->k = k; rs->eqn = 0; rs->r = 0;
    if (!m0) {
      int idx = (int)atomicAdd(nm1, 1u);
      if (idx < MAXM1) m1rows[idx] = (u32)row;
      rpack[row] = 0ull;
    }
  }
  const size_t stride = (size_t)gridDim.x * blockDim.x;
  for (size_t i = (size_t)blockIdx.x * blockDim.x + tid; i < zwords; i += stride) zp[i] = 0;
}

// kC: mode-1 level-0 12-bit count + fixed-point esum + S partials (R3-proven)
__global__ __launch_bounds__(TA) void kC(const float* __restrict__ logits,
                                         const float* __restrict__ temps,
                                         const State* __restrict__ st,
                                         const u32* __restrict__ nm1,
                                         const u32* __restrict__ m1rows,
                                         float* __restrict__ Sparts,
                                         u32* __restrict__ m1c0,
                                         u64* __restrict__ m1e0, int V) {
  u32 n = nm1[0]; if (n > MAXM1) n = MAXM1;
  if (blockIdx.x >= n) return;
  const int row = (int)m1rows[blockIdx.x];
  const int m1 = blockIdx.x, seg = blockIdx.y, tid = threadIdx.x;
  const State* rs = &st[row];
  __shared__ u32 c0[NB];
  __shared__ u64 e0[NB];
  __shared__ float ss[TA];
  for (int i = tid; i < NB; i += TA) { c0[i] = 0; e0[i] = 0ull; }
  __syncthreads();
  const float t = temps[row];
  const float m = rs->m;
  const float* lr = logits + (size_t)row * V;
  const float4* l4 = (const float4*)lr;
  const int n4 = V >> 2;
  const int q0 = (int)((long long)seg * n4 / SM);
  const int q1 = (int)((long long)(seg + 1) * n4 / SM);
  float ls = 0.f;
  for (int i = q0 + tid; i < q1; i += TA) {
    float4 v = l4[i];
    float xs[4] = {v.x / t, v.y / t, v.z / t, v.w / t};
#pragma unroll
    for (int j = 0; j < 4; ++j) {
      float e = expf(xs[j] - m);
      ls += e;
      u32 b = f2key(xs[j]) >> 20;
      atomicAdd(&c0[b], 1u);
      u64 fx = (u64)(e * FXS);
      if (fx) atomicAdd(&e0[b], fx);
    }
  }
  if (seg == SM - 1)
    for (int i = (n4 << 2) + tid; i < V; i += TA) {
      float x = lr[i] / t;
      float e = expf(x - m);
      ls += e;
      u32 b = f2key(x) >> 20;
      atomicAdd(&c0[b], 1u);
      u64 fx = (u64)(e * FXS);
      if (fx) atomicAdd(&e0[b], fx);
    }
  ss[tid] = ls;
  __syncthreads();
  for (int s = TA >> 1; s > 0; s >>= 1) {
    if (tid < s) ss[tid] += ss[tid + s];
    __syncthreads();
  }
  if (tid == 0) Sparts[m1 * SM + seg] = ss[0];
  for (int b = tid; b < NB; b += TA) {
    if (c0[b]) atomicAdd(&m1c0[(size_t)m1 * NB + b], c0[b]);
    if (e0[b]) atomicAdd(&m1e0[(size_t)m1 * NB + b], e0[b]);
  }
}

// kC2: mode-1 level-0 scan -> prefix12, cnt_above, exp_above, S, target
__global__ __launch_bounds__(TA) void kC2(const float* __restrict__ topps,
                                          const u32* __restrict__ nm1,
                                          const u32* __restrict__ m1rows,
                                          const float* __restrict__ Sparts,
                                          const u32* __restrict__ m1c0,
                                          const u64* __restrict__ m1e0,
                                          Aux1* __restrict__ aux1) {
  u32 n = nm1[0]; if (n > MAXM1) n = MAXM1;
  if (blockIdx.x >= n) return;
  const int row = (int)m1rows[blockIdx.x];
  const int m1 = blockIdx.x, tid = threadIdx.x;
  __shared__ u32 cnt[NB];
  __shared__ u64 e0[NB];
  __shared__ ScanSh ax;
  __shared__ u32 spfx;
  __shared__ int sca;
  __shared__ float sea;
  for (int i = tid; i < NB; i += TA) {
    cnt[i] = m1c0[(size_t)m1 * NB + i];
    e0[i] = m1e0[(size_t)m1 * NB + i];
  }
  __syncthreads();
  float S = 0.f;
  for (int j = 0; j < SM; ++j) S += Sparts[m1 * SM + j];
  const float target = topps[row] * S;
  scan_level(cnt, e0, &ax, &spfx, &sca, &sea, target, tid);
  if (tid == 0) {
    Aux1 a; a.pfx = spfx; a.ca = sca; a.ea = sea; a.S = S; a.target = target;
    aux1[m1] = a;
  }
}

// kD: gather all elements of the level-0 crossing bin (parallel over segs)
__global__ __launch_bounds__(TA) void kD(const float* __restrict__ logits,
                                         const float* __restrict__ temps,
                                         const u32* __restrict__ nm1,
                                         const u32* __restrict__ m1rows,
                                         const Aux1* __restrict__ aux1,
                                         u32* __restrict__ gcnt1,
                                         float* __restrict__ g1v,
                                         int* __restrict__ g1i, int V) {
  u32 n = nm1[0]; if (n > MAXM1) n = MAXM1;
  if (blockIdx.x >= n) return;
  const int row = (int)m1rows[blockIdx.x];
  const int m1 = blockIdx.x, seg = blockIdx.y, tid = threadIdx.x;
  const u32 pfx = aux1[m1].pfx;
  const float t = temps[row];
  const float* lr = logits + (size_t)row * V;
  const float4* l4 = (const float4*)lr;
  const int n4 = V >> 2;
  const int q0 = (int)((long long)seg * n4 / SM);
  const int q1 = (int)((long long)(seg + 1) * n4 / SM);
  const size_t base = (size_t)m1 * GB1;
  for (int i = q0 + tid; i < q1; i += TA) {
    float4 v = l4[i];
    float xs[4] = {v.x / t, v.y / t, v.z / t, v.w / t};
#pragma unroll
    for (int j = 0; j < 4; ++j) {
      if ((f2key(xs[j]) >> 20) == pfx) {
        u32 s = atomicAdd(&gcnt1[m1], 1u);
        if (s < GB1) { g1v[base + s] = xs[j]; g1i[base + s] = i * 4 + j; }
      }
    }
  }
  if (seg == SM - 1)
    for (int i = (n4 << 2) + tid; i < V; i += TA) {
      float x = lr[i] / t;
      if ((f2key(x) >> 20) == pfx) {
        u32 s = atomicAdd(&gcnt1[m1], 1u);
        if (s < GB1) { g1v[base + s] = x; g1i[base + s] = i; }
      }
    }
}

// kD2: 10-bit sub-scan on gathered set -> sub-bin -> sort -> exact grouped
// per-copy replay (R1/R3 semantics) -> vstar, r, Z2, eq[]
__global__ __launch_bounds__(TBB) void kD2(const float* __restrict__ topps,
                                           const u32* __restrict__ nm1,
                                           const u32* __restrict__ m1rows,
                                           const Aux1* __restrict__ aux1,
                                           const u32* __restrict__ gcnt1,
                                           const float* __restrict__ g1v,
                                           const int* __restrict__ g1i,
                                           State* __restrict__ st) {
  u32 n = nm1[0]; if (n > MAXM1) n = MAXM1;
  if (blockIdx.x >= n) return;
  const int row = (int)m1rows[blockIdx.x];
  const int m1 = blockIdx.x, tid = threadIdx.x;
  State* rs = &st[row];
  __shared__ u32 cnt1[1024];
  __shared__ u64 fx1[1024];
  __shared__ float subv[SUBC]; __shared__ int subi[SUBC];
  __shared__ float ssv[SUBC]; __shared__ int ssi[SUBC];
  __shared__ int scross, sca1, sns;
  __shared__ float sea1;
  int nf = (int)gcnt1[m1]; if (nf > GB1) nf = GB1;
  if (tid < 1024) { cnt1[tid] = 0; fx1[tid] = 0ull; }
  if (tid == 0) sns = 0;
  __syncthreads();
  const float m = rs->m;
  const size_t base = (size_t)m1 * GB1;
  for (int i = tid; i < nf; i += TBB) {
    float x = g1v[base + i];
    u32 b = (f2key(x) >> 10) & 0x3FFu;
    float e = expf(x - m);
    atomicAdd(&cnt1[b], 1u);
    u64 fx = (u64)(e * FXS);
    if (fx) atomicAdd(&fx1[b], fx);
  }
  __syncthreads();
  if (tid == 0) {
    const float ea0 = aux1[m1].ea;
    const int ca0 = aux1[m1].ca;
    const float target = aux1[m1].target;
    float racc = 0.f; u32 cacc = 0;
    int cross = -1; float cea = 0.f; u32 cca = 0;
    int fb = -1; float fea = 0.f; u32 fca = 0;
    for (int b = 1023; b >= 0; --b) {
      u32 c = cnt1[b];
      if (!c) continue;
      float ebv = (float)fx1[b] * FXI;
      if (ea0 + (racc + ebv) >= target) { cross = b; cea = racc; cca = cacc; break; }
      fb = b; fea = racc; fca = cacc;
      racc += ebv; cacc += c;
    }
    if (cross >= 0) { scross = cross; sea1 = ea0 + cea; sca1 = ca0 + (int)cca; }
    else if (fb >= 0) { scross = fb; sea1 = ea0 + fea; sca1 = ca0 + (int)fca; }
    else { scross = 0; sea1 = ea0; sca1 = ca0; }
  }
  __syncthreads();
  const u32 cb = (u32)scross;
  for (int i = tid; i < nf; i += TBB) {
    float x = g1v[base + i];
    if (((f2key(x) >> 10) & 0x3FFu) == cb) {
      int s = atomicAdd(&sns, 1);
      if (s < SUBC) { subv[s] = x; subi[s] = g1i[base + i]; }
    }
  }
  __syncthreads();
  int ns = sns; if (ns > SUBC) ns = SUBC;
  for (int i = tid; i < ns; i += TBB) {
    float v = subv[i]; int ix = subi[i];
    int rank = 0;
    for (int j = 0; j < ns; ++j) {
      float vj = subv[j]; int ij = subi[j];
      if (vj > v || (vj == v && ij < ix)) rank++;
    }
    ssv[rank] = v; ssi[rank] = ix;
  }
  __syncthreads();
  if (tid == 0) {
    const float S = aux1[m1].S;
    const float p = topps[row];
    float run_n = sea1 / S;
    float run_u = sea1;
    const int have_above = (sca1 > 0);
    u32 lastkey = 0u; int lastr = 0, laststart = -1, anykept = 0;
    u32 vsel = 0u; int rsel = -1, bstart = 0;
    int j = 0;
    while (j < ns) {
      u32 key = f2key(ssv[j]);
      int c = 1;
      while (j + c < ns && f2key(ssv[j + c]) == key) ++c;
      float e = expf(ssv[j] - m);
      float en = e / S;
      int kept = 0;
      for (int q = 0; q < c; ++q) {
        float nn = run_n + en;
        if (nn < p) { run_n = nn; run_u += e; kept++; } else break;
      }
      if (kept == c) { lastkey = key; lastr = c; laststart = j; anykept = 1; j += c; continue; }
      if (kept > 0) { vsel = key; rsel = kept; bstart = j; }
      else if (anykept) { vsel = lastkey; rsel = lastr; bstart = laststart; }
      else if (have_above) { vsel = key; rsel = 0; bstart = j; }
      else { vsel = key; rsel = 1; bstart = j; run_u += e; }
      break;
    }
    if (rsel < 0) {
      if (anykept) { vsel = lastkey; rsel = lastr; bstart = laststart; }
      else if (ns > 0) {
        vsel = f2key(ssv[0]); bstart = 0;
        if (have_above) rsel = 0;
        else { rsel = 1; run_u += expf(ssv[0] - m); }
      } else { vsel = 0u; rsel = 0; bstart = 0; }
    }
    int eqn = rsel;
    if (eqn > EQC) eqn = EQC;
    if (eqn < 0) eqn = 0;
    if (bstart + eqn > ns) eqn = ns - bstart;
    if (eqn < 0) eqn = 0;
    for (int q2 = 0; q2 < eqn; ++q2) rs->eq[q2] = ssi[bstart + q2];
    rs->eqn = eqn; rs->r = rsel; rs->vstar = vsel; rs->Z2 = run_u;
  }
}

// kH: mode-0: merge per-seg candidates, exact radix-select kk-th key,
// compact survivors (key >= key_kk), rank-sort, exact replay, race. (R5-proven)
__global__ __launch_bounds__(TBB) void kH(const float* __restrict__ topps,
                                          const float* __restrict__ noise,
                                          const u32* __restrict__ scnt,
                                          const float* __restrict__ candv,
                                          const int* __restrict__ candi,
                                          const State* __restrict__ st,
                                          int* __restrict__ out, int V) {
  const int row = blockIdx.x, tid = threadIdx.x;
  const State* rs = &st[row];
  if (rs->mode != 0) return;
  __shared__ float gv[GTOT]; __shared__ int gi[GTOT];
  __shared__ float sv[CAPSEG]; __shared__ int si[CAPSEG];
  __shared__ float fv[CAPSEG]; __shared__ int fi[CAPSEG];
  __shared__ float rr[TBB]; __shared__ int ri[TBB];
  __shared__ int offs[SA + 1];
  __shared__ u32 dh[256];
  __shared__ u32 sPrefix; __shared__ int sRemain, sNf;
  __shared__ int sJ; __shared__ float sZ2;
  if (tid == 0) {
    int o = 0;
    for (int s = 0; s < SA; ++s) {
      offs[s] = o;
      int c = (int)scnt[row * SA + s];
      if (c > CAPSEG) c = CAPSEG;
      if (c < 0) c = 0;
      o += c;
    }
    offs[SA] = o;
  }
  __syncthreads();
  const int g = offs[SA];
  for (int s = 0; s < SA; ++s) {
    const int o = offs[s], c = offs[s + 1] - o;
    const size_t cbase = ((size_t)row * SA + s) * CAPSEG;
    for (int i = tid; i < c; i += TBB) { gv[o + i] = candv[cbase + i]; gi[o + i] = candi[cbase + i]; }
  }
  __syncthreads();
  int kk = rs->k; if (kk > 256) kk = 256; if (kk > g) kk = g;
  if (tid == 0) { sPrefix = 0u; sRemain = (kk < 1) ? 1 : kk; }
  __syncthreads();
  for (int pass = 0; pass < 4; ++pass) {
    const int shift = 24 - 8 * pass;
    if (tid < 256) dh[tid] = 0;
    __syncthreads();
    const u32 pref = sPrefix;
    for (int i = tid; i < g; i += TBB) {
      u32 key = f2key(gv[i]);
      if (pass == 0 || (key >> (shift + 8)) == pref)
        atomicAdd(&dh[(key >> shift) & 0xFFu], 1u);
    }
    __syncthreads();
    if (tid == 0) {
      u32 rc = 0; int d = 255;
      for (; d >= 0; --d) {
        if (rc + dh[d] >= (u32)sRemain) break;
        rc += dh[d];
      }
      if (d < 0) d = 0;
      sRemain -= (int)rc;
      sPrefix = (sPrefix << 8) | (u32)d;
      if (pass == 3) sNf = 0;
    }
    __syncthreads();
  }
  const u32 Tk = sPrefix;
  for (int i = tid; i < g; i += TBB) {
    if (f2key(gv[i]) >= Tk) {
      int s = atomicAdd(&sNf, 1);
      if (s < CAPSEG) { fv[s] = gv[i]; fi[s] = gi[i]; }
    }
  }
  __syncthreads();
  int nf = sNf; if (nf > CAPSEG) nf = CAPSEG;
  for (int i = tid; i < nf; i += TBB) {
    float v = fv[i]; int ix = fi[i];
    int rank = 0;
    for (int j = 0; j < nf; ++j) {
      float vj = fv[j]; int ij = fi[j];
      if (vj > v || (vj == v && ij < ix)) rank++;
    }
    sv[rank] = v; si[rank] = ix;
  }
  __syncthreads();
  const float m = rs->m;
  const float p = topps[row];
  if (tid == 0) {
    int keff = rs->k; if (keff > nf) keff = nf;
    int J = 1; float Z2 = 1.f;
    if (nf > 0 && keff > 0) {
      float Zk = 0.f;
      for (int j = 0; j < keff; ++j) Zk += expf(sv[j] - m);
      float c = 0.f; J = 0;
      for (int j = 0; j < keff; ++j) {
        float pr = expf(sv[j] - m) / Zk;
        c += pr;
        if (c < p) J++; else break;
      }
      if (J < 1) J = 1;
      Z2 = 0.f;
      for (int j = 0; j < J; ++j) Z2 += expf(sv[j] - m);
    }
    sJ = J; sZ2 = Z2;
  }
  __syncthreads();
  const int J = sJ; const float Z2 = sZ2;
  float best = -1.f; int bidx = 0x7FFFFFFF;
  for (int j = tid; j < J && j < nf; j += TBB) {
    int ix = si[j];
    float u = noise[(size_t)row * V + ix];
    float q = fmaxf(-logf(u), 1e-10f);
    float pr = expf(sv[j] - m) / Z2;
    float rt = pr / q;
    if (rt > best || (rt == best && ix < bidx)) { best = rt; bidx = ix; }
  }
  rr[tid] = best; ri[tid] = bidx;
  __syncthreads();
  for (int s = TBB >> 1; s > 0; s >>= 1) {
    if (tid < s) {
      float ov = rr[tid + s]; int oi = ri[tid + s];
      if (ov > rr[tid] || (ov == rr[tid] && oi < ri[tid])) { rr[tid] = ov; ri[tid] = oi; }
    }
    __syncthreads();
  }
  if (tid == 0) out[row] = (nf > 0) ? ri[0] : 0;
}

// kI: mode-1 race over full row, packed (ratio_key, ~idx) atomicMax
__global__ __launch_bounds__(TA) void kI(const float* __restrict__ logits,
                                         const float* __restrict__ temps,
                                         const float* __restrict__ noise,
                                         const State* __restrict__ st,
                                         u64* __restrict__ rpack, int V) {
  const int row = blockIdx.x, seg = blockIdx.y, tid = threadIdx.x;
  const State* rs = &st[row];
  if (rs->mode != 1) return;
  __shared__ int eqs[EQC]; __shared__ int seqn;
  __shared__ float rr[TA]; __shared__ int ri[TA];
  if (tid == 0) {
    int nn = rs->eqn; if (nn > EQC) nn = EQC; if (nn < 0) nn = 0;
    seqn = nn;
    for (int i = 0; i < nn; ++i) eqs[i] = rs->eq[i];
  }
  __syncthreads();
  const float t = temps[row];
  const float m = rs->m;
  const float Z2 = rs->Z2;
  const u32 vk = rs->vstar;
  const int eqn = seqn;
  const float* lr = logits + (size_t)row * V;
  const float* ur = noise + (size_t)row * V;
  const float4* l4 = (const float4*)lr;
  const float4* u4 = (const float4*)ur;
  const int n4 = V >> 2;
  const int q0 = (int)((long long)seg * n4 / SM);
  const int q1 = (int)((long long)(seg + 1) * n4 / SM);
  float best = -1.f; int bidx = 0x7FFFFFFF;
  for (int i = q0 + tid; i < q1; i += TA) {
    float4 xv = l4[i];
    float4 uv = u4[i];
    float xs[4] = {xv.x / t, xv.y / t, xv.z / t, xv.w / t};
    float us[4] = {uv.x, uv.y, uv.z, uv.w};
#pragma unroll
    for (int j = 0; j < 4; ++j) {
      u32 key = f2key(xs[j]);
      bool kept = key > vk;
      if (!kept && key == vk) {
        int idx = i * 4 + j;
        for (int e = 0; e < eqn; ++e) if (eqs[e] == idx) { kept = true; break; }
      }
      if (kept) {
        float pr = expf(xs[j] - m) / Z2;
        float q = fmaxf(-logf(us[j]), 1e-10f);
        float rt = pr / q;
        int idx = i * 4 + j;
        if (rt > best || (rt == best && idx < bidx)) { best = rt; bidx = idx; }
      }
    }
  }
  if (seg == SM - 1)
    for (int i = (n4 << 2) + tid; i < V; i += TA) {
      float x = lr[i] / t;
      u32 key = f2key(x);
      bool kept = key > vk;
      if (!kept && key == vk) {
        for (int e = 0; e < eqn; ++e) if (eqs[e] == i) { kept = true; break; }
      }
      if (kept) {
        float pr = expf(x - m) / Z2;
        float q = fmaxf(-logf(ur[i]), 1e-10f);
        float rt = pr / q;
        if (rt > best || (rt == best && i < bidx)) { best = rt; bidx = i; }
      }
    }
  rr[tid] = best; ri[tid] = bidx;
  __syncthreads();
  for (int s = TA >> 1; s > 0; s >>= 1) {
    if (tid < s) {
      float ov = rr[tid + s]; int oi = ri[tid + s];
      if (ov > rr[tid] || (ov == rr[tid] && oi < ri[tid])) { rr[tid] = ov; ri[tid] = oi; }
    }
    __syncthreads();
  }
  if (tid == 0 && rr[0] >= 0.f) {
    u64 pk = ((u64)f2key(rr[0]) << 32) | (u64)(0xFFFFFFFFu - (u32)ri[0]);
    atomicMax(&rpack[row], pk);
  }
}

__global__ void kJ(const State* __restrict__ st, const u64* __restrict__ rpack,
                   int* __restrict__ out, int B) {
  int i = blockIdx.x * blockDim.x + threadIdx.x;
  if (i < B && st[i].mode == 1)
    out[i] = (int)(0xFFFFFFFFu - (u32)(rpack[i] & 0xFFFFFFFFull));
}

extern "C" void kernel_launch(void* const* d_in, const int* in_sizes, int n_in,
                              void* d_out, int out_size, void* d_ws, size_t ws_size,
                              hipStream_t stream) {
  const float* logits = (const float*)d_in[0];
  const float* temps = (const float*)d_in[1];
  const int* topks = (const int*)d_in[2];
  const float* topps = (const float*)d_in[3];
  const float* noise = (const float*)d_in[4];
  int* out = (int*)d_out;
  const int B = in_sizes[1];
  const int V = in_sizes[0] / B;
  (void)n_in; (void)out_size; (void)ws_size;

  u32* w = (u32*)d_ws;
  size_t o = 0;
  float* maxpart = (float*)(w + o); o += (size_t)B * SA;
  u32* scnt = w + o; o += (size_t)B * SA;
  float* candv = (float*)(w + o); o += (size_t)B * SA * CAPSEG;
  int* candi = (int*)(w + o); o += (size_t)B * SA * CAPSEG;
  if (o & 1) o += 1;
  u64* rpack = (u64*)(w + o); o += 2 * (size_t)B;
  u32* nm1 = w + o; o += 1;
  u32* m1rows = w + o; o += MAXM1;
  if (o & 1) o += 1;
  const size_t zbase = o;
  u64* m1e0 = (u64*)(w + o); o += 2 * (size_t)MAXM1 * NB;
  u32* m1c0 = w + o; o += (size_t)MAXM1 * NB;
  u32* gcnt1 = w + o; o += MAXM1;
  const size_t zwords = o - zbase;
  float* Sparts = (float*)(w + o); o += (size_t)MAXM1 * SM;
  Aux1* aux1 = (Aux1*)(w + o); o += (sizeof(Aux1) / 4) * (size_t)MAXM1;
  float* g1v = (float*)(w + o); o += (size_t)MAXM1 * GB1;
  int* g1i = (int*)(w + o); o += (size_t)MAXM1 * GB1;
  State* st = (State*)(w + o);

  kA<<<dim3(B, SA), TA, 0, stream>>>(logits, temps, topks, maxpart, scnt, candv, candi, nm1, V);
  kB<<<B, TBB, 0, stream>>>(topks, maxpart, st, rpack, nm1, m1rows, w + zbase, zwords, V);
  kC<<<dim3(MAXM1, SM), TA, 0, stream>>>(logits, temps, st, nm1, m1rows, Sparts, m1c0, m1e0, V);
  kC2<<<MAXM1, TA, 0, stream>>>(topps, nm1, m1rows, Sparts, m1c0, m1e0, aux1);
  kD<<<dim3(MAXM1, SM), TA, 0, stream>>>(logits, temps, nm1, m1rows, aux1, gcnt1, g1v, g1i, V);
  kD2<<<MAXM1, TBB, 0, stream>>>(topps, nm1, m1rows, aux1, gcnt1, g1v, g1i, st);
  kH<<<B, TBB, 0, stream>>>(topps, noise, scnt, candv, candi, st, out, V);
  kI<<<dim3(B, SM), TA, 0, stream>>>(logits, temps, noise, st, rpack, V);
  kJ<<<(B + 255) / 256, 256, 0, stream>>>(st, rpack, out, B);
}

// Round 7
// 246.204 us; speedup vs baseline: 2.1689x; 1.3157x over previous
//
#include <hip/hip_runtime.h>
#include <math.h>

#define SA 8      /* segments for kA */
#define SM 64     /* segments for mode-1 kernels kC/kD/kI */
#define NB 4096
#define TA 256    /* kA / kI / kC / kC2 / kD threads */
#define TBB 1024  /* kB / kH / kD2 threads */
#define SCT 256   /* scan threads (matches R3 chunk structure exactly) */
#define CH (NB / SCT) /* 16 */
#define CAPSEG 512
#define GTOT (SA * CAPSEG) /* 4096 */
#define MAXM1 16
#define GB1 16384 /* gathered crossing-bin cap per mode-1 row */
#define SUBC 512  /* sub-bin cap */
#define EQC 64
#define FXS 1099511627776.0f /* 2^40 */
#define FXI (1.0f / 1099511627776.0f)

typedef unsigned u32;
typedef unsigned long long u64;

struct State {
  float m, Z2;
  int mode, k, r, eqn;
  u32 vstar;
  int eq[EQC];
};

struct Aux1 {
  u32 pfx;      // 12-bit level-0 prefix
  int ca;       // cnt_above after level 0
  float ea;     // exp_above after level 0
  float S;
  float target; // p * S
};

struct ScanSh {
  u32 axc[SCT]; float axe[SCT];
  u32 sufc[SCT]; float sufe[SCT];
  int cbin[SCT]; u32 cca[SCT]; float cea[SCT];
  int fbin[SCT]; u32 fca[SCT]; float fea[SCT];
};

__device__ __forceinline__ u32 f2key(float f) {
  u32 u = __float_as_uint(f);
  return u ^ ((u >> 31) ? 0xFFFFFFFFu : 0x80000000u);
}
__device__ __forceinline__ float key2f(u32 k) {
  u32 u = (k & 0x80000000u) ? (k ^ 0x80000000u) : ~k;
  return __uint_as_float(u);
}
__device__ __forceinline__ int is_mode0(int k, int V) {
  return (k >= 1 && k <= 256 && k < V);
}

// R3-proven level-0 crossing scan (mode-1), 256-thread structure.
__device__ void scan_level(const u32* cnt, const u64* e0, ScanSh* ax,
                           u32* sprefix, int* scnt_above, float* sexp_above,
                           float target, int tid) {
  if (tid < SCT) {
    u32 cc = 0; float ce = 0.f; const int base = tid * CH;
    for (int j = 0; j < CH; ++j) { cc += cnt[base + j]; ce += (float)e0[base + j] * FXI; }
    ax->axc[tid] = cc; ax->axe[tid] = ce;
  }
  __syncthreads();
  if (tid == 0) {
    u32 rc = 0; float re = 0.f;
    for (int c = SCT - 1; c >= 0; --c) {
      ax->sufc[c] = rc; ax->sufe[c] = re;
      rc += ax->axc[c]; re += ax->axe[c];
    }
  }
  __syncthreads();
  if (tid < SCT) {
    const int base = tid * CH;
    u32 rc = ax->sufc[tid]; float re = ax->sufe[tid];
    int best = -1; u32 bca = 0; float bea = 0.f;
    int fb = -1; u32 ffca = 0; float ffea = 0.f;
    for (int b = base + CH - 1; b >= base; --b) {
      u32 c = cnt[b]; float ebv = (float)e0[b] * FXI;
      bool cross = (c > 0) && ((re + ebv) >= target);
      if (cross && best < 0) { best = b; bca = rc; bea = re; }
      if (c > 0) { fb = b; ffca = rc; ffea = re; }
      rc += c; re += ebv;
    }
    ax->cbin[tid] = best; ax->cca[tid] = bca; ax->cea[tid] = bea;
    ax->fbin[tid] = fb; ax->fca[tid] = ffca; ax->fea[tid] = ffea;
  }
  __syncthreads();
  if (tid == 0) {
    int bsel = -1; u32 ca = 0; float ea = 0.f;
    for (int c = 0; c < SCT; ++c) {
      int b = ax->cbin[c];
      if (b > bsel) { bsel = b; ca = ax->cca[c]; ea = ax->cea[c]; }
    }
    if (bsel < 0) {
      for (int c = 0; c < SCT; ++c) {
        int b = ax->fbin[c];
        if (b >= 0 && (bsel < 0 || b < bsel)) { bsel = b; ca = ax->fca[c]; ea = ax->fea[c]; }
      }
    }
    if (bsel < 0) bsel = 0;
    *sprefix = (u32)bsel;
    *scnt_above = (int)ca;
    *sexp_above = ea;
  }
  __syncthreads();
}

// kA: per-(row,seg): seg max; mode-0 rows also gather seg-local top-k superset
__global__ __launch_bounds__(TA) void kA(const float* __restrict__ logits,
                                         const float* __restrict__ temps,
                                         const int* __restrict__ topks,
                                         float* __restrict__ maxpart,
                                         u32* __restrict__ scnt,
                                         float* __restrict__ candv,
                                         int* __restrict__ candi,
                                         u32* __restrict__ nm1, int V) {
  const int row = blockIdx.x, seg = blockIdx.y, tid = threadIdx.x;
  __shared__ u32 cnt[NB];
  __shared__ float sm[TA];
  __shared__ u32 cs[TA];
  __shared__ int bb[TA];
  __shared__ int lcnt;
  __shared__ u32 sT;
  if (row == 0 && seg == 0 && tid == 0) nm1[0] = 0;
  const int k = topks[row];
  const int m0 = is_mode0(k, V);
  const float t = temps[row];
  const float* lr = logits + (size_t)row * V;
  const float4* l4 = (const float4*)lr;
  const int n4 = V >> 2;
  const int q0 = (int)((long long)seg * n4 / SA);
  const int q1 = (int)((long long)(seg + 1) * n4 / SA);
  float mx = -INFINITY;
  if (m0) {
    for (int i = tid; i < NB; i += TA) cnt[i] = 0;
    if (tid == 0) lcnt = 0;
    __syncthreads();
    for (int i = q0 + tid; i < q1; i += TA) {
      float4 v = l4[i];
      float xs[4] = {v.x / t, v.y / t, v.z / t, v.w / t};
#pragma unroll
      for (int j = 0; j < 4; ++j) {
        mx = fmaxf(mx, xs[j]);
        atomicAdd(&cnt[f2key(xs[j]) >> 20], 1u);
      }
    }
    if (seg == SA - 1)
      for (int i = (n4 << 2) + tid; i < V; i += TA) {
        float x = lr[i] / t;
        mx = fmaxf(mx, x);
        atomicAdd(&cnt[f2key(x) >> 20], 1u);
      }
  } else {
    for (int i = q0 + tid; i < q1; i += TA) {
      float4 v = l4[i];
      mx = fmaxf(mx, fmaxf(fmaxf(v.x, v.y), fmaxf(v.z, v.w)) / t);
    }
    if (seg == SA - 1)
      for (int i = (n4 << 2) + tid; i < V; i += TA) mx = fmaxf(mx, lr[i] / t);
  }
  sm[tid] = mx;
  __syncthreads();
  for (int s = TA >> 1; s > 0; s >>= 1) {
    if (tid < s) sm[tid] = fmaxf(sm[tid], sm[tid + s]);
    __syncthreads();
  }
  if (tid == 0) maxpart[row * SA + seg] = sm[0];
  if (!m0) return;
  {
    u32 cc = 0; const int base = tid * (NB / TA);
    for (int j = 0; j < NB / TA; ++j) cc += cnt[base + j];
    cs[tid] = cc;
  }
  __syncthreads();
  if (tid == 0) {
    u32 rc = 0;
    for (int c = TA - 1; c >= 0; --c) { u32 tmp = cs[c]; cs[c] = rc; rc += tmp; }
  }
  __syncthreads();
  const int kk = (k > 256) ? 256 : k;
  {
    const int base = tid * (NB / TA);
    u32 rc = cs[tid]; int best = -1;
    for (int b = base + NB / TA - 1; b >= base; --b) {
      u32 c = cnt[b];
      if (c && best < 0 && (int)(rc + c) >= kk) best = b;
      rc += c;
    }
    bb[tid] = best;
  }
  __syncthreads();
  if (tid == 0) {
    int bsel = -1;
    for (int c = 0; c < TA; ++c) if (bb[c] > bsel) bsel = bb[c];
    if (bsel < 0) { for (int b = 0; b < NB; ++b) if (cnt[b]) { bsel = b; break; } }
    if (bsel < 0) bsel = 0;
    sT = ((u32)bsel) << 20;
  }
  __syncthreads();
  const u32 T = sT;
  const size_t cbase = ((size_t)row * SA + seg) * CAPSEG;
  for (int i = q0 + tid; i < q1; i += TA) {
    float4 v = l4[i];
    float xs[4] = {v.x / t, v.y / t, v.z / t, v.w / t};
#pragma unroll
    for (int j = 0; j < 4; ++j) {
      if (f2key(xs[j]) >= T) {
        int s = atomicAdd(&lcnt, 1);
        if (s < CAPSEG) { candv[cbase + s] = xs[j]; candi[cbase + s] = i * 4 + j; }
      }
    }
  }
  if (seg == SA - 1)
    for (int i = (n4 << 2) + tid; i < V; i += TA) {
      float x = lr[i] / t;
      if (f2key(x) >= T) {
        int s = atomicAdd(&lcnt, 1);
        if (s < CAPSEG) { candv[cbase + s] = x; candi[cbase + s] = i; }
      }
    }
  __syncthreads();
  if (tid == 0) { int n = lcnt; if (n > CAPSEG) n = CAPSEG; scnt[row * SA + seg] = (u32)n; }
}

// kB: light per-row: mode + m + compact mode-1 rows + zero mode-1 accumulators
__global__ __launch_bounds__(TBB) void kB(const int* __restrict__ topks,
                                          const float* __restrict__ maxpart,
                                          State* __restrict__ st,
                                          u64* __restrict__ rpack,
                                          u32* __restrict__ nm1,
                                          u32* __restrict__ m1rows,
                                          u32* __restrict__ zp, size_t zwords, int V) {
  const int row = blockIdx.x, tid = threadIdx.x;
  State* rs = &st[row];
  const int k = topks[row];
  const int m0 = is_mode0(k, V);
  if (tid == 0) {
    float m = maxpart[row * SA];
    for (int j = 1; j < SA; ++j) m = fmaxf(m, maxpart[row * SA + j]);
    rs->m = m; rs->mode = m0 ? 0 : 1; rs->k = k; rs->eqn = 0; rs->r = 0;
    if (!m0) {
      int idx = (int)atomicAdd(nm1, 1u);
      if (idx < MAXM1) m1rows[idx] = (u32)row;
      rpack[row] = 0ull;
    }
  }
  const size_t stride = (size_t)gridDim.x * blockDim.x;
  for (size_t i = (size_t)blockIdx.x * blockDim.x + tid; i < zwords; i += stride) zp[i] = 0;
}

// kC: mode-1 level-0 12-bit count + fixed-point esum + S partials (R3-proven)
__global__ __launch_bounds__(TA) void kC(const float* __restrict__ logits,
                                         const float* __restrict__ temps,
                                         const State* __restrict__ st,
                                         const u32* __restrict__ nm1,
                                         const u32* __restrict__ m1rows,
                                         float* __restrict__ Sparts,
                                         u32* __restrict__ m1c0,
                                         u64* __restrict__ m1e0, int V) {
  u32 n = nm1[0]; if (n > MAXM1) n = MAXM1;
  if (blockIdx.x >= n) return;
  const int row = (int)m1rows[blockIdx.x];
  const int m1 = blockIdx.x, seg = blockIdx.y, tid = threadIdx.x;
  const State* rs = &st[row];
  __shared__ u32 c0[NB];
  __shared__ u64 e0[NB];
  __shared__ float ss[TA];
  for (int i = tid; i < NB; i += TA) { c0[i] = 0; e0[i] = 0ull; }
  __syncthreads();
  const float t = temps[row];
  const float m = rs->m;
  const float* lr = logits + (size_t)row * V;
  const float4* l4 = (const float4*)lr;
  const int n4 = V >> 2;
  const int q0 = (int)((long long)seg * n4 / SM);
  const int q1 = (int)((long long)(seg + 1) * n4 / SM);
  float ls = 0.f;
  for (int i = q0 + tid; i < q1; i += TA) {
    float4 v = l4[i];
    float xs[4] = {v.x / t, v.y / t, v.z / t, v.w / t};
#pragma unroll
    for (int j = 0; j < 4; ++j) {
      float e = expf(xs[j] - m);
      ls += e;
      u32 b = f2key(xs[j]) >> 20;
      atomicAdd(&c0[b], 1u);
      u64 fx = (u64)(e * FXS);
      if (fx) atomicAdd(&e0[b], fx);
    }
  }
  if (seg == SM - 1)
    for (int i = (n4 << 2) + tid; i < V; i += TA) {
      float x = lr[i] / t;
      float e = expf(x - m);
      ls += e;
      u32 b = f2key(x) >> 20;
      atomicAdd(&c0[b], 1u);
      u64 fx = (u64)(e * FXS);
      if (fx) atomicAdd(&e0[b], fx);
    }
  ss[tid] = ls;
  __syncthreads();
  for (int s = TA >> 1; s > 0; s >>= 1) {
    if (tid < s) ss[tid] += ss[tid + s];
    __syncthreads();
  }
  if (tid == 0) Sparts[m1 * SM + seg] = ss[0];
  for (int b = tid; b < NB; b += TA) {
    if (c0[b]) atomicAdd(&m1c0[(size_t)m1 * NB + b], c0[b]);
    if (e0[b]) atomicAdd(&m1e0[(size_t)m1 * NB + b], e0[b]);
  }
}

// kC2: mode-1 level-0 scan -> prefix12, cnt_above, exp_above, S, target
__global__ __launch_bounds__(TA) void kC2(const float* __restrict__ topps,
                                          const u32* __restrict__ nm1,
                                          const u32* __restrict__ m1rows,
                                          const float* __restrict__ Sparts,
                                          const u32* __restrict__ m1c0,
                                          const u64* __restrict__ m1e0,
                                          Aux1* __restrict__ aux1) {
  u32 n = nm1[0]; if (n > MAXM1) n = MAXM1;
  if (blockIdx.x >= n) return;
  const int row = (int)m1rows[blockIdx.x];
  const int m1 = blockIdx.x, tid = threadIdx.x;
  __shared__ u32 cnt[NB];
  __shared__ u64 e0[NB];
  __shared__ ScanSh ax;
  __shared__ u32 spfx;
  __shared__ int sca;
  __shared__ float sea;
  for (int i = tid; i < NB; i += TA) {
    cnt[i] = m1c0[(size_t)m1 * NB + i];
    e0[i] = m1e0[(size_t)m1 * NB + i];
  }
  __syncthreads();
  float S = 0.f;
  for (int j = 0; j < SM; ++j) S += Sparts[m1 * SM + j];
  const float target = topps[row] * S;
  scan_level(cnt, e0, &ax, &spfx, &sca, &sea, target, tid);
  if (tid == 0) {
    Aux1 a; a.pfx = spfx; a.ca = sca; a.ea = sea; a.S = S; a.target = target;
    aux1[m1] = a;
  }
}

// kD: gather all elements of the level-0 crossing bin (parallel over segs)
__global__ __launch_bounds__(TA) void kD(const float* __restrict__ logits,
                                         const float* __restrict__ temps,
                                         const u32* __restrict__ nm1,
                                         const u32* __restrict__ m1rows,
                                         const Aux1* __restrict__ aux1,
                                         u32* __restrict__ gcnt1,
                                         float* __restrict__ g1v,
                                         int* __restrict__ g1i, int V) {
  u32 n = nm1[0]; if (n > MAXM1) n = MAXM1;
  if (blockIdx.x >= n) return;
  const int row = (int)m1rows[blockIdx.x];
  const int m1 = blockIdx.x, seg = blockIdx.y, tid = threadIdx.x;
  const u32 pfx = aux1[m1].pfx;
  const float t = temps[row];
  const float* lr = logits + (size_t)row * V;
  const float4* l4 = (const float4*)lr;
  const int n4 = V >> 2;
  const int q0 = (int)((long long)seg * n4 / SM);
  const int q1 = (int)((long long)(seg + 1) * n4 / SM);
  const size_t base = (size_t)m1 * GB1;
  for (int i = q0 + tid; i < q1; i += TA) {
    float4 v = l4[i];
    float xs[4] = {v.x / t, v.y / t, v.z / t, v.w / t};
#pragma unroll
    for (int j = 0; j < 4; ++j) {
      if ((f2key(xs[j]) >> 20) == pfx) {
        u32 s = atomicAdd(&gcnt1[m1], 1u);
        if (s < GB1) { g1v[base + s] = xs[j]; g1i[base + s] = i * 4 + j; }
      }
    }
  }
  if (seg == SM - 1)
    for (int i = (n4 << 2) + tid; i < V; i += TA) {
      float x = lr[i] / t;
      if ((f2key(x) >> 20) == pfx) {
        u32 s = atomicAdd(&gcnt1[m1], 1u);
        if (s < GB1) { g1v[base + s] = x; g1i[base + s] = i; }
      }
    }
}

// kD2: 10-bit sub-scan on gathered set (parallel u64 suffix sums) -> sub-bin
// -> sort -> exact grouped per-copy replay -> vstar, r, Z2, eq[]
__global__ __launch_bounds__(TBB) void kD2(const float* __restrict__ topps,
                                           const u32* __restrict__ nm1,
                                           const u32* __restrict__ m1rows,
                                           const Aux1* __restrict__ aux1,
                                           const u32* __restrict__ gcnt1,
                                           const float* __restrict__ g1v,
                                           const int* __restrict__ g1i,
                                           State* __restrict__ st) {
  u32 n = nm1[0]; if (n > MAXM1) n = MAXM1;
  if (blockIdx.x >= n) return;
  const int row = (int)m1rows[blockIdx.x];
  const int m1 = blockIdx.x, tid = threadIdx.x;
  State* rs = &st[row];
  __shared__ u32 cnt1[1024];
  __shared__ u64 fx1[1024];
  __shared__ u32 csuf[1024];
  __shared__ u64 esuf[1024];
  __shared__ float subv[SUBC]; __shared__ int subi[SUBC];
  __shared__ float ssv[SUBC]; __shared__ int ssi[SUBC];
  __shared__ int scross, sfb, sca1, sns;
  __shared__ float sea1;
  int nf = (int)gcnt1[m1]; if (nf > GB1) nf = GB1;
  cnt1[tid] = 0; fx1[tid] = 0ull;
  if (tid == 0) { sns = 0; scross = -1; sfb = 0x7FFFFFFF; }
  __syncthreads();
  const float m = rs->m;
  const size_t base = (size_t)m1 * GB1;
  for (int i = tid; i < nf; i += TBB) {
    float x = g1v[base + i];
    u32 b = (f2key(x) >> 10) & 0x3FFu;
    float e = expf(x - m);
    atomicAdd(&cnt1[b], 1u);
    u64 fx = (u64)(e * FXS);
    if (fx) atomicAdd(&fx1[b], fx);
  }
  __syncthreads();
  // parallel inclusive suffix sums (exact integer)
  csuf[tid] = cnt1[tid]; esuf[tid] = fx1[tid];
  __syncthreads();
  for (int stp = 1; stp < 1024; stp <<= 1) {
    u32 ca_ = 0; u64 ea_ = 0ull;
    if (tid + stp < 1024) { ca_ = csuf[tid + stp]; ea_ = esuf[tid + stp]; }
    __syncthreads();
    csuf[tid] += ca_; esuf[tid] += ea_;
    __syncthreads();
  }
  {
    const float ea0 = aux1[m1].ea;
    const float target = aux1[m1].target;
    u32 c = cnt1[tid];
    if (c) {
      float racc = (float)(esuf[tid] - fx1[tid]) * FXI;  // exact suffix above bin
      float ebv = (float)fx1[tid] * FXI;
      if (ea0 + (racc + ebv) >= target) atomicMax(&scross, tid);
      atomicMin(&sfb, tid);
    }
  }
  __syncthreads();
  if (tid == 0) {
    const float ea0 = aux1[m1].ea;
    const int ca0 = aux1[m1].ca;
    int cb = scross;
    if (cb < 0) cb = (sfb != 0x7FFFFFFF) ? sfb : 0;
    u32 cAbove = csuf[cb] - cnt1[cb];
    float eAbove = (float)(esuf[cb] - fx1[cb]) * FXI;
    scross = cb;
    sea1 = ea0 + eAbove;
    sca1 = ca0 + (int)cAbove;
  }
  __syncthreads();
  const u32 cb = (u32)scross;
  for (int i = tid; i < nf; i += TBB) {
    float x = g1v[base + i];
    if (((f2key(x) >> 10) & 0x3FFu) == cb) {
      int s = atomicAdd(&sns, 1);
      if (s < SUBC) { subv[s] = x; subi[s] = g1i[base + i]; }
    }
  }
  __syncthreads();
  int ns = sns; if (ns > SUBC) ns = SUBC;
  for (int i = tid; i < ns; i += TBB) {
    float v = subv[i]; int ix = subi[i];
    int rank = 0;
    for (int j = 0; j < ns; ++j) {
      float vj = subv[j]; int ij = subi[j];
      if (vj > v || (vj == v && ij < ix)) rank++;
    }
    ssv[rank] = v; ssi[rank] = ix;
  }
  __syncthreads();
  if (tid == 0) {
    const float S = aux1[m1].S;
    const float p = topps[row];
    float run_n = sea1 / S;
    float run_u = sea1;
    const int have_above = (sca1 > 0);
    u32 lastkey = 0u; int lastr = 0, laststart = -1, anykept = 0;
    u32 vsel = 0u; int rsel = -1, bstart = 0;
    int j = 0;
    while (j < ns) {
      u32 key = f2key(ssv[j]);
      int c = 1;
      while (j + c < ns && f2key(ssv[j + c]) == key) ++c;
      float e = expf(ssv[j] - m);
      float en = e / S;
      int kept = 0;
      for (int q = 0; q < c; ++q) {
        float nn = run_n + en;
        if (nn < p) { run_n = nn; run_u += e; kept++; } else break;
      }
      if (kept == c) { lastkey = key; lastr = c; laststart = j; anykept = 1; j += c; continue; }
      if (kept > 0) { vsel = key; rsel = kept; bstart = j; }
      else if (anykept) { vsel = lastkey; rsel = lastr; bstart = laststart; }
      else if (have_above) { vsel = key; rsel = 0; bstart = j; }
      else { vsel = key; rsel = 1; bstart = j; run_u += e; }
      break;
    }
    if (rsel < 0) {
      if (anykept) { vsel = lastkey; rsel = lastr; bstart = laststart; }
      else if (ns > 0) {
        vsel = f2key(ssv[0]); bstart = 0;
        if (have_above) rsel = 0;
        else { rsel = 1; run_u += expf(ssv[0] - m); }
      } else { vsel = 0u; rsel = 0; bstart = 0; }
    }
    int eqn = rsel;
    if (eqn > EQC) eqn = EQC;
    if (eqn < 0) eqn = 0;
    if (bstart + eqn > ns) eqn = ns - bstart;
    if (eqn < 0) eqn = 0;
    for (int q2 = 0; q2 < eqn; ++q2) rs->eq[q2] = ssi[bstart + q2];
    rs->eqn = eqn; rs->r = rsel; rs->vstar = vsel; rs->Z2 = run_u;
  }
}

// kH: mode-0: merge per-seg candidates, exact PARALLEL radix-select kk-th key,
// compact survivors (key >= key_kk), rank-sort, exact replay (no break), race.
__global__ __launch_bounds__(TBB) void kH(const float* __restrict__ topps,
                                          const float* __restrict__ noise,
                                          const u32* __restrict__ scnt,
                                          const float* __restrict__ candv,
                                          const int* __restrict__ candi,
                                          const State* __restrict__ st,
                                          int* __restrict__ out, int V) {
  const int row = blockIdx.x, tid = threadIdx.x;
  const State* rs = &st[row];
  if (rs->mode != 0) return;
  __shared__ float gv[GTOT]; __shared__ int gi[GTOT];
  __shared__ float sv[CAPSEG]; __shared__ int si[CAPSEG];
  __shared__ float fv[CAPSEG]; __shared__ int fi[CAPSEG];
  __shared__ float pe[CAPSEG];
  __shared__ float rr[TBB]; __shared__ int ri[TBB];
  __shared__ int offs[SA + 1];
  __shared__ u32 dh[256]; __shared__ u32 dsufx[256];
  __shared__ u32 sPrefix; __shared__ int sRemain, sNf, sDig;
  __shared__ int sJ; __shared__ float sZ2;
  if (tid == 0) {
    int o = 0;
    for (int s = 0; s < SA; ++s) {
      offs[s] = o;
      int c = (int)scnt[row * SA + s];
      if (c > CAPSEG) c = CAPSEG;
      if (c < 0) c = 0;
      o += c;
    }
    offs[SA] = o;
  }
  __syncthreads();
  const int g = offs[SA];
  for (int s = 0; s < SA; ++s) {
    const int o = offs[s], c = offs[s + 1] - o;
    const size_t cbase = ((size_t)row * SA + s) * CAPSEG;
    for (int i = tid; i < c; i += TBB) { gv[o + i] = candv[cbase + i]; gi[o + i] = candi[cbase + i]; }
  }
  __syncthreads();
  int kk = rs->k; if (kk > 256) kk = 256; if (kk > g) kk = g;
  if (tid == 0) { sPrefix = 0u; sRemain = (kk < 1) ? 1 : kk; }
  __syncthreads();
  for (int pass = 0; pass < 4; ++pass) {
    const int shift = 24 - 8 * pass;
    if (tid < 256) dh[tid] = 0;
    if (tid == 0) sDig = -1;
    __syncthreads();
    const u32 pref = sPrefix;
    for (int i = tid; i < g; i += TBB) {
      u32 key = f2key(gv[i]);
      if (pass == 0 || (key >> (shift + 8)) == pref)
        atomicAdd(&dh[(key >> shift) & 0xFFu], 1u);
    }
    __syncthreads();
    // parallel inclusive suffix sum over 256 digits (exact integer)
    if (tid < 256) dsufx[tid] = dh[tid];
    __syncthreads();
    for (int stp = 1; stp < 256; stp <<= 1) {
      u32 addv = 0;
      if (tid < 256 && tid + stp < 256) addv = dsufx[tid + stp];
      __syncthreads();
      if (tid < 256) dsufx[tid] += addv;
      __syncthreads();
    }
    if (tid < 256) {
      u32 excl = dsufx[tid] - dh[tid];
      u32 rem = (u32)sRemain;
      if (dh[tid] && excl < rem && excl + dh[tid] >= rem) sDig = tid;  // unique
    }
    __syncthreads();
    if (tid == 0) {
      int d = sDig; if (d < 0) d = 0;
      u32 excl = dsufx[d] - dh[d];
      sRemain -= (int)excl;
      sPrefix = (sPrefix << 8) | (u32)d;
      if (pass == 3) sNf = 0;
    }
    __syncthreads();
  }
  const u32 Tk = sPrefix;
  for (int i = tid; i < g; i += TBB) {
    if (f2key(gv[i]) >= Tk) {
      int s = atomicAdd(&sNf, 1);
      if (s < CAPSEG) { fv[s] = gv[i]; fi[s] = gi[i]; }
    }
  }
  __syncthreads();
  int nf = sNf; if (nf > CAPSEG) nf = CAPSEG;
  for (int i = tid; i < nf; i += TBB) {
    float v = fv[i]; int ix = fi[i];
    int rank = 0;
    for (int j = 0; j < nf; ++j) {
      float vj = fv[j]; int ij = fi[j];
      if (vj > v || (vj == v && ij < ix)) rank++;
    }
    sv[rank] = v; si[rank] = ix;
  }
  __syncthreads();
  const float m = rs->m;
  const float p = topps[row];
  int keff = rs->k; if (keff > nf) keff = nf;
  for (int j = tid; j < keff; j += TBB) pe[j] = expf(sv[j] - m);
  __syncthreads();
  if (tid == 0) {
    int J = 1; float Z2 = 1.f;
    if (nf > 0 && keff > 0) {
      float Zk = 0.f;
      for (int j = 0; j < keff; ++j) Zk += pe[j];
      float c = 0.f; int Jc = 0;
      for (int j = 0; j < keff; ++j) {  // no break: cumsum non-decreasing
        float pr = pe[j] / Zk;
        c += pr;
        if (c < p) Jc++;
      }
      if (Jc < 1) Jc = 1;
      J = Jc;
      Z2 = 0.f;
      for (int j = 0; j < J && j < keff; ++j) Z2 += pe[j];
    }
    sJ = J; sZ2 = Z2;
  }
  __syncthreads();
  const int J = sJ; const float Z2 = sZ2;
  float best = -1.f; int bidx = 0x7FFFFFFF;
  for (int j = tid; j < J && j < nf; j += TBB) {
    int ix = si[j];
    float u = noise[(size_t)row * V + ix];
    float q = fmaxf(-logf(u), 1e-10f);
    float pr = pe[j] / Z2;
    float rt = pr / q;
    if (rt > best || (rt == best && ix < bidx)) { best = rt; bidx = ix; }
  }
  rr[tid] = best; ri[tid] = bidx;
  __syncthreads();
  for (int s = TBB >> 1; s > 0; s >>= 1) {
    if (tid < s) {
      float ov = rr[tid + s]; int oi = ri[tid + s];
      if (ov > rr[tid] || (ov == rr[tid] && oi < ri[tid])) { rr[tid] = ov; ri[tid] = oi; }
    }
    __syncthreads();
  }
  if (tid == 0) out[row] = (nf > 0) ? ri[0] : 0;
}

// kI: mode-1 race over full row, packed (ratio_key, ~idx) atomicMax
__global__ __launch_bounds__(TA) void kI(const float* __restrict__ logits,
                                         const float* __restrict__ temps,
                                         const float* __restrict__ noise,
                                         const State* __restrict__ st,
                                         u64* __restrict__ rpack, int V) {
  const int row = blockIdx.x, seg = blockIdx.y, tid = threadIdx.x;
  const State* rs = &st[row];
  if (rs->mode != 1) return;
  __shared__ int eqs[EQC]; __shared__ int seqn;
  __shared__ float rr[TA]; __shared__ int ri[TA];
  if (tid == 0) {
    int nn = rs->eqn; if (nn > EQC) nn = EQC; if (nn < 0) nn = 0;
    seqn = nn;
    for (int i = 0; i < nn; ++i) eqs[i] = rs->eq[i];
  }
  __syncthreads();
  const float t = temps[row];
  const float m = rs->m;
  const float Z2 = rs->Z2;
  const u32 vk = rs->vstar;
  const int eqn = seqn;
  const float* lr = logits + (size_t)row * V;
  const float* ur = noise + (size_t)row * V;
  const float4* l4 = (const float4*)lr;
  const float4* u4 = (const float4*)ur;
  const int n4 = V >> 2;
  const int q0 = (int)((long long)seg * n4 / SM);
  const int q1 = (int)((long long)(seg + 1) * n4 / SM);
  float best = -1.f; int bidx = 0x7FFFFFFF;
  for (int i = q0 + tid; i < q1; i += TA) {
    float4 xv = l4[i];
    float4 uv = u4[i];
    float xs[4] = {xv.x / t, xv.y / t, xv.z / t, xv.w / t};
    float us[4] = {uv.x, uv.y, uv.z, uv.w};
#pragma unroll
    for (int j = 0; j < 4; ++j) {
      u32 key = f2key(xs[j]);
      bool kept = key > vk;
      if (!kept && key == vk) {
        int idx = i * 4 + j;
        for (int e = 0; e < eqn; ++e) if (eqs[e] == idx) { kept = true; break; }
      }
      if (kept) {
        float pr = expf(xs[j] - m) / Z2;
        float q = fmaxf(-logf(us[j]), 1e-10f);
        float rt = pr / q;
        int idx = i * 4 + j;
        if (rt > best || (rt == best && idx < bidx)) { best = rt; bidx = idx; }
      }
    }
  }
  if (seg == SM - 1)
    for (int i = (n4 << 2) + tid; i < V; i += TA) {
      float x = lr[i] / t;
      u32 key = f2key(x);
      bool kept = key > vk;
      if (!kept && key == vk) {
        for (int e = 0; e < eqn; ++e) if (eqs[e] == i) { kept = true; break; }
      }
      if (kept) {
        float pr = expf(x - m) / Z2;
        float q = fmaxf(-logf(ur[i]), 1e-10f);
        float rt = pr / q;
        if (rt > best || (rt == best && i < bidx)) { best = rt; bidx = i; }
      }
    }
  rr[tid] = best; ri[tid] = bidx;
  __syncthreads();
  for (int s = TA >> 1; s > 0; s >>= 1) {
    if (tid < s) {
      float ov = rr[tid + s]; int oi = ri[tid + s];
      if (ov > rr[tid] || (ov == rr[tid] && oi < ri[tid])) { rr[tid] = ov; ri[tid] = oi; }
    }
    __syncthreads();
  }
  if (tid == 0 && rr[0] >= 0.f) {
    u64 pk = ((u64)f2key(rr[0]) << 32) | (u64)(0xFFFFFFFFu - (u32)ri[0]);
    atomicMax(&rpack[row], pk);
  }
}

__global__ void kJ(const State* __restrict__ st, const u64* __restrict__ rpack,
                   int* __restrict__ out, int B) {
  int i = blockIdx.x * blockDim.x + threadIdx.x;
  if (i < B && st[i].mode == 1)
    out[i] = (int)(0xFFFFFFFFu - (u32)(rpack[i] & 0xFFFFFFFFull));
}

extern "C" void kernel_launch(void* const* d_in, const int* in_sizes, int n_in,
                              void* d_out, int out_size, void* d_ws, size_t ws_size,
                              hipStream_t stream) {
  const float* logits = (const float*)d_in[0];
  const float* temps = (const float*)d_in[1];
  const int* topks = (const int*)d_in[2];
  const float* topps = (const float*)d_in[3];
  const float* noise = (const float*)d_in[4];
  int* out = (int*)d_out;
  const int B = in_sizes[1];
  const int V = in_sizes[0] / B;
  (void)n_in; (void)out_size; (void)ws_size;

  u32* w = (u32*)d_ws;
  size_t o = 0;
  float* maxpart = (float*)(w + o); o += (size_t)B * SA;
  u32* scnt = w + o; o += (size_t)B * SA;
  float* candv = (float*)(w + o); o += (size_t)B * SA * CAPSEG;
  int* candi = (int*)(w + o); o += (size_t)B * SA * CAPSEG;
  if (o & 1) o += 1;
  u64* rpack = (u64*)(w + o); o += 2 * (size_t)B;
  u32* nm1 = w + o; o += 1;
  u32* m1rows = w + o; o += MAXM1;
  if (o & 1) o += 1;
  const size_t zbase = o;
  u64* m1e0 = (u64*)(w + o); o += 2 * (size_t)MAXM1 * NB;
  u32* m1c0 = w + o; o += (size_t)MAXM1 * NB;
  u32* gcnt1 = w + o; o += MAXM1;
  const size_t zwords = o - zbase;
  float* Sparts = (float*)(w + o); o += (size_t)MAXM1 * SM;
  Aux1* aux1 = (Aux1*)(w + o); o += (sizeof(Aux1) / 4) * (size_t)MAXM1;
  float* g1v = (float*)(w + o); o += (size_t)MAXM1 * GB1;
  int* g1i = (int*)(w + o); o += (size_t)MAXM1 * GB1;
  State* st = (State*)(w + o);

  kA<<<dim3(B, SA), TA, 0, stream>>>(logits, temps, topks, maxpart, scnt, candv, candi, nm1, V);
  kB<<<B, TBB, 0, stream>>>(topks, maxpart, st, rpack, nm1, m1rows, w + zbase, zwords, V);
  kC<<<dim3(MAXM1, SM), TA, 0, stream>>>(logits, temps, st, nm1, m1rows, Sparts, m1c0, m1e0, V);
  kC2<<<MAXM1, TA, 0, stream>>>(topps, nm1, m1rows, Sparts, m1c0, m1e0, aux1);
  kD<<<dim3(MAXM1, SM), TA, 0, stream>>>(logits, temps, nm1, m1rows, aux1, gcnt1, g1v, g1i, V);
  kD2<<<MAXM1, TBB, 0, stream>>>(topps, nm1, m1rows, aux1, gcnt1, g1v, g1i, st);
  kH<<<B, TBB, 0, stream>>>(topps, noise, scnt, candv, candi, st, out, V);
  kI<<<dim3(B, SM), TA, 0, stream>>>(logits, temps, noise, st, rpack, V);
  kJ<<<(B + 255) / 256, 256, 0, stream>>>(st, rpack, out, B);
}